// Round 7
// baseline (346.389 us; speedup 1.0000x reference)
//
#include <hip/hip_runtime.h>

#define N_NODES 100000
#define N_EDGES 1600000
#define IN_DIM 256
#define HIDDEN 128
#define OUT_DIM 64

#define NBIN 391       // coarse bins of 256 nodes: ceil(100000/256)
#define NBLK3 256      // histogram/scatter blocks
#define CHUNK 6250     // edges per block: N_EDGES / NBLK3 exactly
#define NMAT (NBIN * NBLK3)      // 100096 = scan length
#define NBLK_SCAN (NMAT / 256)   // 391 exactly
#define CAP 6144       // max edges per bin (mean 4096, sigma 64 -> 32 sigma margin)

typedef __bf16 bf16x8 __attribute__((ext_vector_type(8)));
typedef __bf16 bf16x4 __attribute__((ext_vector_type(4)));
typedef float f32x4 __attribute__((ext_vector_type(4)));

// ---------------------------------------------------------------------------
// P1: per-(bin,block) histogram. cnt2[k*NBLK3 + b] = #edges of block b in bin k
// ---------------------------------------------------------------------------
__launch_bounds__(256)
__global__ void k_hist(const int* __restrict__ dst, int* __restrict__ cnt2) {
    __shared__ int hist[NBIN];
    for (int i = threadIdx.x; i < NBIN; i += 256) hist[i] = 0;
    __syncthreads();
    int base = blockIdx.x * CHUNK;
    for (int i = threadIdx.x; i < CHUNK; i += 256)
        atomicAdd(&hist[dst[base + i] >> 8], 1);
    __syncthreads();
    for (int k = threadIdx.x; k < NBIN; k += 256)
        cnt2[k * NBLK3 + blockIdx.x] = hist[k];
}

// ---------------------------------------------------------------------------
// P2: 2-kernel scan: per-block exclusive scan + block-sum exclusive scan.
// The bsum[k] correction is folded into consumers (k_scatter_bins, k_fine).
// ---------------------------------------------------------------------------
__global__ void k_scan1(int* __restrict__ a, int* __restrict__ bsum) {
    __shared__ int tmp[256];
    int t = threadIdx.x;
    int i = blockIdx.x * 256 + t;
    int v = a[i];
    tmp[t] = v;
    __syncthreads();
    #pragma unroll
    for (int off = 1; off < 256; off <<= 1) {
        int p = (t >= off) ? tmp[t - off] : 0;
        __syncthreads();
        tmp[t] += p;
        __syncthreads();
    }
    a[i] = tmp[t] - v;  // exclusive within bin-row
    if (t == 255) bsum[blockIdx.x] = tmp[255];
}

__global__ void k_scan2(int* __restrict__ bsum) {
    __shared__ int tmp[512];
    int t = threadIdx.x;
    int v = (t < NBLK_SCAN) ? bsum[t] : 0;
    tmp[t] = v;
    __syncthreads();
    #pragma unroll
    for (int off = 1; off < 512; off <<= 1) {
        int p = (t >= off) ? tmp[t - off] : 0;
        __syncthreads();
        tmp[t] += p;
        __syncthreads();
    }
    if (t < NBLK_SCAN) bsum[t] = tmp[t] - v;
}

// ---------------------------------------------------------------------------
// P3: scatter edges into bin-grouped ebuf; packed entry: src*256 | (dst&255)
// ---------------------------------------------------------------------------
__launch_bounds__(256)
__global__ void k_scatter_bins(const int* __restrict__ src, const int* __restrict__ dst,
                               const int* __restrict__ off2, const int* __restrict__ bsum,
                               unsigned int* __restrict__ ebuf) {
    __shared__ int cursor[NBIN];
    for (int k = threadIdx.x; k < NBIN; k += 256)
        cursor[k] = off2[k * NBLK3 + blockIdx.x] + bsum[k];
    __syncthreads();
    int base = blockIdx.x * CHUNK;
    for (int i = threadIdx.x; i < CHUNK; i += 256) {
        int s = src[base + i], d = dst[base + i];
        int pos = atomicAdd(&cursor[d >> 8], 1);
        ebuf[pos] = ((unsigned)s << 8) | (unsigned)(d & 255);
    }
}

// ---------------------------------------------------------------------------
// P4: fine counting-sort within each bin; fuses dinv + rowstart production.
// ---------------------------------------------------------------------------
__launch_bounds__(256)
__global__ void k_fine(const unsigned int* __restrict__ ebuf, const int* __restrict__ off2,
                       const int* __restrict__ bsum,
                       int* __restrict__ esrc, int* __restrict__ rowstart,
                       float* __restrict__ dinv) {
    __shared__ int hist[256];
    __shared__ int tmp[256];
    __shared__ int nodeoff[256];
    __shared__ int cursor[256];
    __shared__ unsigned int ed[CAP];
    __shared__ int sOut[CAP];

    const int k = blockIdx.x;
    const int t = threadIdx.x;
    const int e0 = off2[k * NBLK3] + bsum[k];
    const int e1 = (k + 1 < NBIN) ? off2[(k + 1) * NBLK3] + bsum[k + 1] : N_EDGES;
    int m = e1 - e0;
    if (m > CAP) m = CAP;  // safety clamp (statistically unreachable)

    hist[t] = 0;
    __syncthreads();
    for (int i = t; i < m; i += 256) {
        unsigned v = ebuf[e0 + i];
        ed[i] = v;
        atomicAdd(&hist[v & 255], 1);
    }
    __syncthreads();

    int v = hist[t];
    tmp[t] = v;
    __syncthreads();
    #pragma unroll
    for (int off = 1; off < 256; off <<= 1) {
        int p = (t >= off) ? tmp[t - off] : 0;
        __syncthreads();
        tmp[t] += p;
        __syncthreads();
    }
    nodeoff[t] = tmp[t] - v;
    cursor[t] = tmp[t] - v;
    __syncthreads();

    for (int i = t; i < m; i += 256) {
        unsigned e = ed[i];
        int pos = atomicAdd(&cursor[e & 255], 1);
        sOut[pos] = (int)(e >> 8);
    }
    __syncthreads();

    for (int i = t; i < m; i += 256) esrc[e0 + i] = sOut[i];

    int n = k * 256 + t;
    if (n < N_NODES) {
        rowstart[n] = e0 + nodeoff[t];
        dinv[n] = rsqrtf((float)hist[t] + 1.0f);
    }
    if (k == 0 && t == 0) rowstart[N_NODES] = N_EDGES;
}

// ---------------------------------------------------------------------------
// GEMM1 (bf16 MFMA): H[M][128] = bf16(X[M][256]) @ bf16(W1[256][128])
// 512 threads (8 waves), 128 rows/block, grid 782.  W1 staged in TWO 32KB
// halves.  A direct global->reg; barrier only at stage points.
// ---------------------------------------------------------------------------
__device__ __forceinline__ int bsw1h(int c, int kk) {   // kk in [0,128)
    return c * 128 + (kk ^ ((c & 7) << 3));
}

__launch_bounds__(512, 4)
__global__ void k_gemm1(const float* __restrict__ X, const float* __restrict__ W1,
                        __bf16* __restrict__ H) {
    __shared__ __attribute__((aligned(16))) __bf16 Bs[128 * 128];  // 32 KB

    const int t = threadIdx.x;
    const int wave = t >> 6;
    const int lane = t & 63;
    const int lm = lane & 15;
    const int q = lane >> 4;
    const int row0 = blockIdx.x * 128;
    const int g = row0 + wave * 16 + lm;   // the row this lane loads

    f32x4 acc[8] = {};

    for (int half = 0; half < 2; ++half) {
        __syncthreads();   // everyone done reading previous Bs image
        for (int p = 0; p < 4; ++p) {
            int i = t + 512 * p;        // 0..2047
            int c = i & 127;            // column
            int kg = i >> 7;            // k-group 0..15
            float v[8];
            #pragma unroll
            for (int j = 0; j < 8; ++j)
                v[j] = W1[(half * 128 + kg * 8 + j) * HIDDEN + c];
            bf16x8 w;
            #pragma unroll
            for (int j = 0; j < 8; ++j) w[j] = (__bf16)v[j];
            *(bf16x8*)&Bs[bsw1h(c, kg * 8)] = w;
        }
        __syncthreads();

        #pragma unroll
        for (int k0 = 0; k0 < 128; k0 += 32) {
            float4 v0 = make_float4(0.f, 0.f, 0.f, 0.f), v1 = v0;
            if (g < N_NODES) {
                const float* p = &X[(size_t)g * IN_DIM + half * 128 + k0 + q * 8];
                v0 = *(const float4*)p;
                v1 = *(const float4*)(p + 4);
            }
            bf16x8 a;
            a[0] = (__bf16)v0.x; a[1] = (__bf16)v0.y;
            a[2] = (__bf16)v0.z; a[3] = (__bf16)v0.w;
            a[4] = (__bf16)v1.x; a[5] = (__bf16)v1.y;
            a[6] = (__bf16)v1.z; a[7] = (__bf16)v1.w;
            #pragma unroll
            for (int ni = 0; ni < 8; ++ni) {
                bf16x8 bfr = *(const bf16x8*)&Bs[bsw1h(ni * 16 + lm, k0 + q * 8)];
                acc[ni] = __builtin_amdgcn_mfma_f32_16x16x32_bf16(a, bfr, acc[ni], 0, 0, 0);
            }
        }
    }

    #pragma unroll
    for (int r = 0; r < 4; ++r) {
        int grow = row0 + wave * 16 + q * 4 + r;
        if (grow < N_NODES) {
            #pragma unroll
            for (int ni = 0; ni < 8; ++ni)
                H[grow * HIDDEN + ni * 16 + lm] = (__bf16)acc[ni][r];
        }
    }
}

// ---------------------------------------------------------------------------
// FUSED gather1 + GEMM2: per block of 128 dst nodes,
//   phase 0: stage W2 (16 KB LDS, swizzled)
//   phase 1: R2-form gather (16 lanes x bf16x8 per node, x4 unroll) ->
//            relu(agg+b1) rows into 32 KB LDS tile As (chunk-XOR swizzle)
//   barrier
//   phase 2: gemm2 MFMA, A-fragments from LDS, H2[128 rows][64] to global.
// AGG never touches HBM (saves 51.2 MB round trip + one launch).
// Numerics: same bf16 rounding point and accumulation order as the split
// version -> bit-identical.
// ---------------------------------------------------------------------------
__device__ __forceinline__ int bsw2(int c, int kk) {
    return c * 128 + (kk ^ ((c & 7) << 3));
}

__launch_bounds__(512, 6)
__global__ void k_gather1g2(const int* __restrict__ rowstart, const int* __restrict__ esrc,
                            const float* __restrict__ dinv,
                            const __bf16* __restrict__ H, const float* __restrict__ b1,
                            const float* __restrict__ W2,
                            __bf16* __restrict__ H2) {
    __shared__ __attribute__((aligned(16))) __bf16 As[128 * 128];  // 32 KB agg tile
    __shared__ __attribute__((aligned(16))) __bf16 Bs[64 * 128];   // 16 KB W2

    const int t = threadIdx.x;
    const int row0 = blockIdx.x * 128;

    // ---- phase 0: stage W2 (independent of phase 1) ----
    for (int p = 0; p < 2; ++p) {
        int i = t + 512 * p;        // 0..1023
        int c = i & 63;             // column
        int kg = i >> 6;            // k-group 0..15
        float v[8];
        #pragma unroll
        for (int j = 0; j < 8; ++j)
            v[j] = W2[(kg * 8 + j) * OUT_DIM + c];
        bf16x8 w;
        #pragma unroll
        for (int j = 0; j < 8; ++j) w[j] = (__bf16)v[j];
        *(bf16x8*)&Bs[bsw2(c, kg * 8)] = w;
    }

    // ---- phase 1: gather 128 nodes, 32 nodes per pass (16 lanes/node) ----
    const int jc = t & 15;         // 16B chunk index within row
    const int j = jc * 8;          // feature offset
    for (int pass = 0; pass < 4; ++pass) {
        int nl = pass * 32 + (t >> 4);    // local row 0..127
        int n = row0 + nl;
        bf16x8 o = {};
        if (n < N_NODES) {
            float dn = dinv[n];
            float s = dn * dn;
            bf16x8 h = *(const bf16x8*)&H[n * HIDDEN + j];
            float acc[8];
            #pragma unroll
            for (int i = 0; i < 8; ++i) acc[i] = (float)h[i] * s;

            int p0 = rowstart[n], p1 = rowstart[n + 1];
            int p = p0;
            for (; p + 3 < p1; p += 4) {
                int s0 = esrc[p + 0], s1 = esrc[p + 1], s2 = esrc[p + 2], s3 = esrc[p + 3];
                float c0 = dinv[s0] * dn, c1 = dinv[s1] * dn;
                float c2 = dinv[s2] * dn, c3 = dinv[s3] * dn;
                bf16x8 v0 = *(const bf16x8*)&H[s0 * HIDDEN + j];
                bf16x8 v1 = *(const bf16x8*)&H[s1 * HIDDEN + j];
                bf16x8 v2 = *(const bf16x8*)&H[s2 * HIDDEN + j];
                bf16x8 v3 = *(const bf16x8*)&H[s3 * HIDDEN + j];
                #pragma unroll
                for (int i = 0; i < 8; ++i) acc[i] = fmaf((float)v0[i], c0, acc[i]);
                #pragma unroll
                for (int i = 0; i < 8; ++i) acc[i] = fmaf((float)v1[i], c1, acc[i]);
                #pragma unroll
                for (int i = 0; i < 8; ++i) acc[i] = fmaf((float)v2[i], c2, acc[i]);
                #pragma unroll
                for (int i = 0; i < 8; ++i) acc[i] = fmaf((float)v3[i], c3, acc[i]);
            }
            for (; p < p1; ++p) {
                int sidx = esrc[p];
                float c = dinv[sidx] * dn;
                bf16x8 v = *(const bf16x8*)&H[sidx * HIDDEN + j];
                #pragma unroll
                for (int i = 0; i < 8; ++i) acc[i] = fmaf((float)v[i], c, acc[i]);
            }

            float4 bb0 = *(const float4*)&b1[j];
            float4 bb1 = *(const float4*)&b1[j + 4];
            o[0] = (__bf16)fmaxf(acc[0] + bb0.x, 0.f);
            o[1] = (__bf16)fmaxf(acc[1] + bb0.y, 0.f);
            o[2] = (__bf16)fmaxf(acc[2] + bb0.z, 0.f);
            o[3] = (__bf16)fmaxf(acc[3] + bb0.w, 0.f);
            o[4] = (__bf16)fmaxf(acc[4] + bb1.x, 0.f);
            o[5] = (__bf16)fmaxf(acc[5] + bb1.y, 0.f);
            o[6] = (__bf16)fmaxf(acc[6] + bb1.z, 0.f);
            o[7] = (__bf16)fmaxf(acc[7] + bb1.w, 0.f);
        }
        // chunk-XOR swizzle within the row (bijective): write 16B chunk
        *(bf16x8*)&As[nl * 128 + (jc ^ (nl & 7)) * 8] = o;
    }
    __syncthreads();   // As + Bs ready

    // ---- phase 2: MFMA, wave w owns rows 16w..16w+15 ----
    const int wave = t >> 6;
    const int lane = t & 63;
    const int lm = lane & 15;
    const int q = lane >> 4;
    const int rl = wave * 16 + lm;   // local A row this lane reads

    f32x4 acc2[4] = {};
    #pragma unroll
    for (int k0 = 0; k0 < HIDDEN; k0 += 32) {
        int c = (k0 >> 3) + q;       // chunk 0..15
        bf16x8 a = *(const bf16x8*)&As[rl * 128 + (c ^ (rl & 7)) * 8];
        #pragma unroll
        for (int ni = 0; ni < 4; ++ni) {
            bf16x8 bfr = *(const bf16x8*)&Bs[bsw2(ni * 16 + lm, k0 + q * 8)];
            acc2[ni] = __builtin_amdgcn_mfma_f32_16x16x32_bf16(a, bfr, acc2[ni], 0, 0, 0);
        }
    }

    #pragma unroll
    for (int r = 0; r < 4; ++r) {
        int grow = row0 + wave * 16 + q * 4 + r;
        if (grow < N_NODES) {
            #pragma unroll
            for (int ni = 0; ni < 4; ++ni)
                H2[grow * OUT_DIM + ni * 16 + lm] = (__bf16)acc2[ni][r];
        }
    }
}

// ---------------------------------------------------------------------------
// gather layer2: OUT[n] = relu( sum coef*H2[src] + dinv^2*H2[n] + b2 )  (f32)
// R2 form: 8 lanes x bf16x8 per node, 32 nodes/block, x4 unroll.
// ---------------------------------------------------------------------------
__launch_bounds__(256)
__global__ void k_gather2(const int* __restrict__ rowstart, const int* __restrict__ esrc,
                          const float* __restrict__ dinv,
                          const __bf16* __restrict__ H2, const float* __restrict__ b2,
                          float* __restrict__ OUT) {
    int n = blockIdx.x * 32 + (threadIdx.x >> 3);
    if (n >= N_NODES) return;
    int j = (threadIdx.x & 7) * 8;

    float dn = dinv[n];
    float s = dn * dn;
    bf16x8 h = *(const bf16x8*)&H2[n * OUT_DIM + j];
    float acc[8];
    #pragma unroll
    for (int i = 0; i < 8; ++i) acc[i] = (float)h[i] * s;

    int p0 = rowstart[n], p1 = rowstart[n + 1];
    int p = p0;
    for (; p + 3 < p1; p += 4) {
        int s0 = esrc[p + 0], s1 = esrc[p + 1], s2 = esrc[p + 2], s3 = esrc[p + 3];
        float c0 = dinv[s0] * dn, c1 = dinv[s1] * dn;
        float c2 = dinv[s2] * dn, c3 = dinv[s3] * dn;
        bf16x8 v0 = *(const bf16x8*)&H2[s0 * OUT_DIM + j];
        bf16x8 v1 = *(const bf16x8*)&H2[s1 * OUT_DIM + j];
        bf16x8 v2 = *(const bf16x8*)&H2[s2 * OUT_DIM + j];
        bf16x8 v3 = *(const bf16x8*)&H2[s3 * OUT_DIM + j];
        #pragma unroll
        for (int i = 0; i < 8; ++i) acc[i] = fmaf((float)v0[i], c0, acc[i]);
        #pragma unroll
        for (int i = 0; i < 8; ++i) acc[i] = fmaf((float)v1[i], c1, acc[i]);
        #pragma unroll
        for (int i = 0; i < 8; ++i) acc[i] = fmaf((float)v2[i], c2, acc[i]);
        #pragma unroll
        for (int i = 0; i < 8; ++i) acc[i] = fmaf((float)v3[i], c3, acc[i]);
    }
    for (; p < p1; ++p) {
        int sidx = esrc[p];
        float c = dinv[sidx] * dn;
        bf16x8 v = *(const bf16x8*)&H2[sidx * OUT_DIM + j];
        #pragma unroll
        for (int i = 0; i < 8; ++i) acc[i] = fmaf((float)v[i], c, acc[i]);
    }

    float4 bb0 = *(const float4*)&b2[j];
    float4 bb1 = *(const float4*)&b2[j + 4];
    float4 o0, o1;
    o0.x = fmaxf(acc[0] + bb0.x, 0.f);
    o0.y = fmaxf(acc[1] + bb0.y, 0.f);
    o0.z = fmaxf(acc[2] + bb0.z, 0.f);
    o0.w = fmaxf(acc[3] + bb0.w, 0.f);
    o1.x = fmaxf(acc[4] + bb1.x, 0.f);
    o1.y = fmaxf(acc[5] + bb1.y, 0.f);
    o1.z = fmaxf(acc[6] + bb1.z, 0.f);
    o1.w = fmaxf(acc[7] + bb1.w, 0.f);
    *(float4*)&OUT[n * OUT_DIM + j] = o0;
    *(float4*)&OUT[n * OUT_DIM + j + 4] = o1;
}

extern "C" void kernel_launch(void* const* d_in, const int* in_sizes, int n_in,
                              void* d_out, int out_size, void* d_ws, size_t ws_size,
                              hipStream_t stream) {
    const float* x  = (const float*)d_in[0];
    const int* ei   = (const int*)d_in[1];
    const float* W1 = (const float*)d_in[2];
    const float* b1 = (const float*)d_in[3];
    const float* W2 = (const float*)d_in[4];
    const float* b2 = (const float*)d_in[5];
    float* out = (float*)d_out;

    const int* src = ei;
    const int* dst = ei + N_EDGES;

    char* ws = (char*)d_ws;
    int*          cnt2     = (int*)         (ws + 0x000000);   // 400,384 B (becomes off2)
    int*          bsum     = (int*)         (ws + 0x080000);   // 1,564 B
    int*          rowstart = (int*)         (ws + 0x090000);   // 400,004 B
    float*        dinv     = (float*)       (ws + 0x100000);   // 400,000 B
    unsigned int* ebuf     = (unsigned int*)(ws + 0x180000);   // 6.4 MB
    int*          esrc     = (int*)         (ws + 0x800000);   // 6.4 MB
    __bf16*       h1       = (__bf16*)      (ws + 0xE80000);   // 25.6 MB
    __bf16*       h2       = (__bf16*)      (ws + 0x4280000);  // 12.8 MB

    // CSR build (two-level counting sort; no random global scatters)
    k_hist<<<NBLK3, 256, 0, stream>>>(dst, cnt2);
    k_scan1<<<NBLK_SCAN, 256, 0, stream>>>(cnt2, bsum);
    k_scan2<<<1, 512, 0, stream>>>(bsum);
    k_scatter_bins<<<NBLK3, 256, 0, stream>>>(src, dst, cnt2, bsum, ebuf);
    k_fine<<<NBIN, 256, 0, stream>>>(ebuf, cnt2, bsum, esrc, rowstart, dinv);

    // layer 1
    k_gemm1<<<(N_NODES + 127) / 128, 512, 0, stream>>>(x, W1, h1);
    // fused gather1 + gemm2  (AGG never hits HBM)
    k_gather1g2<<<(N_NODES + 127) / 128, 512, 0, stream>>>(rowstart, esrc, dinv,
                                                           h1, b1, W2, h2);
    // layer 2 aggregation
    k_gather2<<<(N_NODES + 31) / 32, 256, 0, stream>>>(rowstart, esrc, dinv, h2, b2, out);
}

// Round 8
// 333.856 us; speedup vs baseline: 1.0375x; 1.0375x over previous
//
#include <hip/hip_runtime.h>

#define N_NODES 100000
#define N_EDGES 1600000
#define IN_DIM 256
#define HIDDEN 128
#define OUT_DIM 64

#define NBIN 391       // coarse bins of 256 nodes: ceil(100000/256)
#define NBLK3 256      // histogram/scatter blocks
#define CHUNK 6250     // edges per block: N_EDGES / NBLK3 exactly
#define NMAT (NBIN * NBLK3)      // 100096 = scan length
#define NBLK_SCAN (NMAT / 256)   // 391 exactly
#define CAP 6144       // max edges per bin (mean 4096, sigma 64 -> 32 sigma margin)

// gemm1 passenger-tile distribution across the CSR chain (782 tiles total)
#define G1_TILES 782
#define G_HIST  160
#define G_SCAN1 120
#define G_SCAN2 60
#define G_SCAT  160
#define G_FINE  282
#define OFF_HIST  0
#define OFF_SCAN1 160
#define OFF_SCAN2 280
#define OFF_SCAT  340
#define OFF_FINE  500

typedef __bf16 bf16x8 __attribute__((ext_vector_type(8)));
typedef __bf16 bf16x4 __attribute__((ext_vector_type(4)));
typedef float f32x4 __attribute__((ext_vector_type(4)));

// ---------------------------------------------------------------------------
// GEMM1 tile as a device function (512 threads): H[bid*128..+128][128] =
// bf16(X @ W1).  W1 staged in TWO 32KB halves into Bs (swizzled b128 writes,
// coalesced reads).  A direct global->reg.  Identical math to the R6 kernel.
// ---------------------------------------------------------------------------
__device__ __forceinline__ int bsw1h(int c, int kk) {   // kk in [0,128)
    return c * 128 + (kk ^ ((c & 7) << 3));
}

__device__ __forceinline__ void gemm1_tile(const float* __restrict__ X,
                                           const float* __restrict__ W1,
                                           __bf16* __restrict__ H,
                                           int bid, __bf16* Bs) {
    const int t = threadIdx.x;
    const int wave = t >> 6;
    const int lane = t & 63;
    const int lm = lane & 15;
    const int q = lane >> 4;
    const int row0 = bid * 128;
    const int g = row0 + wave * 16 + lm;   // the row this lane loads

    f32x4 acc[8] = {};

    for (int half = 0; half < 2; ++half) {
        __syncthreads();   // everyone done reading previous Bs image
        for (int p = 0; p < 4; ++p) {
            int i = t + 512 * p;        // 0..2047
            int c = i & 127;            // column
            int kg = i >> 7;            // k-group 0..15
            float v[8];
            #pragma unroll
            for (int j = 0; j < 8; ++j)
                v[j] = W1[(half * 128 + kg * 8 + j) * HIDDEN + c];
            bf16x8 w;
            #pragma unroll
            for (int j = 0; j < 8; ++j) w[j] = (__bf16)v[j];
            *(bf16x8*)&Bs[bsw1h(c, kg * 8)] = w;
        }
        __syncthreads();

        #pragma unroll
        for (int k0 = 0; k0 < 128; k0 += 32) {
            float4 v0 = make_float4(0.f, 0.f, 0.f, 0.f), v1 = v0;
            if (g < N_NODES) {
                const float* p = &X[(size_t)g * IN_DIM + half * 128 + k0 + q * 8];
                v0 = *(const float4*)p;
                v1 = *(const float4*)(p + 4);
            }
            bf16x8 a;
            a[0] = (__bf16)v0.x; a[1] = (__bf16)v0.y;
            a[2] = (__bf16)v0.z; a[3] = (__bf16)v0.w;
            a[4] = (__bf16)v1.x; a[5] = (__bf16)v1.y;
            a[6] = (__bf16)v1.z; a[7] = (__bf16)v1.w;
            #pragma unroll
            for (int ni = 0; ni < 8; ++ni) {
                bf16x8 bfr = *(const bf16x8*)&Bs[bsw1h(ni * 16 + lm, k0 + q * 8)];
                acc[ni] = __builtin_amdgcn_mfma_f32_16x16x32_bf16(a, bfr, acc[ni], 0, 0, 0);
            }
        }
    }

    #pragma unroll
    for (int r = 0; r < 4; ++r) {
        int grow = row0 + wave * 16 + q * 4 + r;
        if (grow < N_NODES) {
            #pragma unroll
            for (int ni = 0; ni < 8; ++ni)
                H[grow * HIDDEN + ni * 16 + lm] = (__bf16)acc[ni][r];
        }
    }
}

// ---------------------------------------------------------------------------
// P1 + gemm passengers: per-(bin,block) histogram (blocks < NBLK3), else a
// gemm1 tile.  Branch is block-uniform -> barriers safe.
// ---------------------------------------------------------------------------
__global__ __launch_bounds__(512, 4)
void k_hist_g(const int* __restrict__ dst, int* __restrict__ cnt2,
              const float* __restrict__ X, const float* __restrict__ W1,
              __bf16* __restrict__ H) {
    __shared__ __attribute__((aligned(16))) char smem[32768];
    if (blockIdx.x < NBLK3) {
        int* hist = (int*)smem;
        int t = threadIdx.x;
        for (int i = t; i < NBIN; i += 512) hist[i] = 0;
        __syncthreads();
        int base = blockIdx.x * CHUNK;
        for (int i = t; i < CHUNK; i += 512)
            atomicAdd(&hist[dst[base + i] >> 8], 1);
        __syncthreads();
        for (int k = t; k < NBIN; k += 512)
            cnt2[k * NBLK3 + blockIdx.x] = hist[k];
    } else {
        gemm1_tile(X, W1, H, OFF_HIST + (int)blockIdx.x - NBLK3, (__bf16*)smem);
    }
}

// ---------------------------------------------------------------------------
// P2a + passengers: per-block exclusive scan (256 elems, threads>=256 idle
// but execute matching barriers).
// ---------------------------------------------------------------------------
__global__ __launch_bounds__(512, 4)
void k_scan1_g(int* __restrict__ a, int* __restrict__ bsum,
               const float* __restrict__ X, const float* __restrict__ W1,
               __bf16* __restrict__ H) {
    __shared__ __attribute__((aligned(16))) char smem[32768];
    if (blockIdx.x < NBLK_SCAN) {
        int* tmp = (int*)smem;
        int t = threadIdx.x;
        int i = blockIdx.x * 256 + t;
        int v = 0;
        if (t < 256) { v = a[i]; tmp[t] = v; }
        __syncthreads();
        #pragma unroll
        for (int off = 1; off < 256; off <<= 1) {
            int p = (t >= off && t < 256) ? tmp[t - off] : 0;
            __syncthreads();
            if (t < 256) tmp[t] += p;
            __syncthreads();
        }
        if (t < 256) a[i] = tmp[t] - v;   // exclusive within bin-row
        if (t == 255) bsum[blockIdx.x] = tmp[255];
    } else {
        gemm1_tile(X, W1, H, OFF_SCAN1 + (int)blockIdx.x - NBLK_SCAN, (__bf16*)smem);
    }
}

// ---------------------------------------------------------------------------
// P2b + passengers: block-sum exclusive scan (single CSR block).
// ---------------------------------------------------------------------------
__global__ __launch_bounds__(512, 4)
void k_scan2_g(int* __restrict__ bsum,
               const float* __restrict__ X, const float* __restrict__ W1,
               __bf16* __restrict__ H) {
    __shared__ __attribute__((aligned(16))) char smem[32768];
    if (blockIdx.x == 0) {
        int* tmp = (int*)smem;   // 512 ints
        int t = threadIdx.x;
        int v = (t < NBLK_SCAN) ? bsum[t] : 0;
        tmp[t] = v;
        __syncthreads();
        #pragma unroll
        for (int off = 1; off < 512; off <<= 1) {
            int p = (t >= off) ? tmp[t - off] : 0;
            __syncthreads();
            tmp[t] += p;
            __syncthreads();
        }
        if (t < NBLK_SCAN) bsum[t] = tmp[t] - v;
    } else {
        gemm1_tile(X, W1, H, OFF_SCAN2 + (int)blockIdx.x - 1, (__bf16*)smem);
    }
}

// ---------------------------------------------------------------------------
// P3 + passengers: scatter edges into bin-grouped ebuf.
// packed entry: src*256 | (dst & 255); bsum[k] folded into cursor init.
// ---------------------------------------------------------------------------
__global__ __launch_bounds__(512, 4)
void k_scatter_g(const int* __restrict__ src, const int* __restrict__ dst,
                 const int* __restrict__ off2, const int* __restrict__ bsum,
                 unsigned int* __restrict__ ebuf,
                 const float* __restrict__ X, const float* __restrict__ W1,
                 __bf16* __restrict__ H) {
    __shared__ __attribute__((aligned(16))) char smem[32768];
    if (blockIdx.x < NBLK3) {
        int* cursor = (int*)smem;
        int t = threadIdx.x;
        for (int k = t; k < NBIN; k += 512)
            cursor[k] = off2[k * NBLK3 + blockIdx.x] + bsum[k];
        __syncthreads();
        int base = blockIdx.x * CHUNK;
        for (int i = t; i < CHUNK; i += 512) {
            int s = src[base + i], d = dst[base + i];
            int pos = atomicAdd(&cursor[d >> 8], 1);
            ebuf[pos] = ((unsigned)s << 8) | (unsigned)(d & 255);
        }
    } else {
        gemm1_tile(X, W1, H, OFF_SCAT + (int)blockIdx.x - NBLK3, (__bf16*)smem);
    }
}

// ---------------------------------------------------------------------------
// P4 + passengers: fine counting-sort within each bin; fuses dinv + rowstart.
// ---------------------------------------------------------------------------
struct FineSm {
    int hist[256];
    int tmp[256];
    int nodeoff[256];
    int cursor[256];
    unsigned int ed[CAP];
    int sOut[CAP];
};   // 53,248 B

__global__ __launch_bounds__(512, 4)
void k_fine_g(const unsigned int* __restrict__ ebuf, const int* __restrict__ off2,
              const int* __restrict__ bsum,
              int* __restrict__ esrc, int* __restrict__ rowstart,
              float* __restrict__ dinv,
              const float* __restrict__ X, const float* __restrict__ W1,
              __bf16* __restrict__ H) {
    __shared__ __attribute__((aligned(16))) char smem[sizeof(FineSm)];
    if (blockIdx.x < NBIN) {
        FineSm* sm = (FineSm*)smem;
        const int k = blockIdx.x;
        const int t = threadIdx.x;
        const int e0 = off2[k * NBLK3] + bsum[k];
        const int e1 = (k + 1 < NBIN) ? off2[(k + 1) * NBLK3] + bsum[k + 1] : N_EDGES;
        int m = e1 - e0;
        if (m > CAP) m = CAP;  // safety clamp (statistically unreachable)

        if (t < 256) sm->hist[t] = 0;
        __syncthreads();
        for (int i = t; i < m; i += 512) {
            unsigned v = ebuf[e0 + i];
            sm->ed[i] = v;
            atomicAdd(&sm->hist[v & 255], 1);
        }
        __syncthreads();

        int v = (t < 256) ? sm->hist[t] : 0;
        if (t < 256) sm->tmp[t] = v;
        __syncthreads();
        #pragma unroll
        for (int off = 1; off < 256; off <<= 1) {
            int p = (t >= off && t < 256) ? sm->tmp[t - off] : 0;
            __syncthreads();
            if (t < 256) sm->tmp[t] += p;
            __syncthreads();
        }
        if (t < 256) {
            sm->nodeoff[t] = sm->tmp[t] - v;
            sm->cursor[t] = sm->tmp[t] - v;
        }
        __syncthreads();

        for (int i = t; i < m; i += 512) {
            unsigned e = sm->ed[i];
            int pos = atomicAdd(&sm->cursor[e & 255], 1);
            sm->sOut[pos] = (int)(e >> 8);
        }
        __syncthreads();

        for (int i = t; i < m; i += 512) esrc[e0 + i] = sm->sOut[i];

        if (t < 256) {
            int n = k * 256 + t;
            if (n < N_NODES) {
                rowstart[n] = e0 + sm->nodeoff[t];
                dinv[n] = rsqrtf((float)sm->hist[t] + 1.0f);
            }
        }
        if (k == 0 && t == 0) rowstart[N_NODES] = N_EDGES;
    } else {
        gemm1_tile(X, W1, H, OFF_FINE + (int)blockIdx.x - NBIN, (__bf16*)smem);
    }
}

// ---------------------------------------------------------------------------
// gather layer1: AGG[n] = bf16(relu( sum coef*H[src] + dinv^2*H[n] + b1 ))
// R2 form: 16 lanes x bf16x8 per node, 16 nodes/block, x4 unroll (VGPR 28).
// ---------------------------------------------------------------------------
__launch_bounds__(256)
__global__ void k_gather1(const int* __restrict__ rowstart, const int* __restrict__ esrc,
                          const float* __restrict__ dinv,
                          const __bf16* __restrict__ H, const float* __restrict__ b1,
                          __bf16* __restrict__ AGG) {
    int n = blockIdx.x * 16 + (threadIdx.x >> 4);
    if (n >= N_NODES) return;
    int j = (threadIdx.x & 15) * 8;

    float dn = dinv[n];
    float s = dn * dn;
    bf16x8 h = *(const bf16x8*)&H[n * HIDDEN + j];
    float acc[8];
    #pragma unroll
    for (int i = 0; i < 8; ++i) acc[i] = (float)h[i] * s;

    int p0 = rowstart[n], p1 = rowstart[n + 1];
    int p = p0;
    for (; p + 3 < p1; p += 4) {
        int s0 = esrc[p + 0], s1 = esrc[p + 1], s2 = esrc[p + 2], s3 = esrc[p + 3];
        float c0 = dinv[s0] * dn, c1 = dinv[s1] * dn;
        float c2 = dinv[s2] * dn, c3 = dinv[s3] * dn;
        bf16x8 v0 = *(const bf16x8*)&H[s0 * HIDDEN + j];
        bf16x8 v1 = *(const bf16x8*)&H[s1 * HIDDEN + j];
        bf16x8 v2 = *(const bf16x8*)&H[s2 * HIDDEN + j];
        bf16x8 v3 = *(const bf16x8*)&H[s3 * HIDDEN + j];
        #pragma unroll
        for (int i = 0; i < 8; ++i) acc[i] = fmaf((float)v0[i], c0, acc[i]);
        #pragma unroll
        for (int i = 0; i < 8; ++i) acc[i] = fmaf((float)v1[i], c1, acc[i]);
        #pragma unroll
        for (int i = 0; i < 8; ++i) acc[i] = fmaf((float)v2[i], c2, acc[i]);
        #pragma unroll
        for (int i = 0; i < 8; ++i) acc[i] = fmaf((float)v3[i], c3, acc[i]);
    }
    for (; p < p1; ++p) {
        int sidx = esrc[p];
        float c = dinv[sidx] * dn;
        bf16x8 v = *(const bf16x8*)&H[sidx * HIDDEN + j];
        #pragma unroll
        for (int i = 0; i < 8; ++i) acc[i] = fmaf((float)v[i], c, acc[i]);
    }

    float4 bb0 = *(const float4*)&b1[j];
    float4 bb1 = *(const float4*)&b1[j + 4];
    bf16x8 o;
    o[0] = (__bf16)fmaxf(acc[0] + bb0.x, 0.f);
    o[1] = (__bf16)fmaxf(acc[1] + bb0.y, 0.f);
    o[2] = (__bf16)fmaxf(acc[2] + bb0.z, 0.f);
    o[3] = (__bf16)fmaxf(acc[3] + bb0.w, 0.f);
    o[4] = (__bf16)fmaxf(acc[4] + bb1.x, 0.f);
    o[5] = (__bf16)fmaxf(acc[5] + bb1.y, 0.f);
    o[6] = (__bf16)fmaxf(acc[6] + bb1.z, 0.f);
    o[7] = (__bf16)fmaxf(acc[7] + bb1.w, 0.f);
    *(bf16x8*)&AGG[n * HIDDEN + j] = o;
}

// ---------------------------------------------------------------------------
// GEMM2 (bf16 MFMA): H2[M][64] = AGG[M][128] @ bf16(W2[128][64])
// R6 form: 128 rows/block, grid 782, LDS 16KB, (512,8).
// ---------------------------------------------------------------------------
__device__ __forceinline__ int bsw2(int c, int kk) {
    return c * 128 + (kk ^ ((c & 7) << 3));
}

__launch_bounds__(512, 8)
__global__ void k_gemm2(const __bf16* __restrict__ AGG, const float* __restrict__ W2,
                        __bf16* __restrict__ H2) {
    __shared__ __attribute__((aligned(16))) __bf16 Bs[64 * 128];  // 16 KB

    const int t = threadIdx.x;
    const int wave = t >> 6;
    const int lane = t & 63;
    const int lm = lane & 15;
    const int q = lane >> 4;
    const int row0 = blockIdx.x * 128;
    const int g = row0 + wave * 16 + lm;

    for (int p = 0; p < 2; ++p) {
        int i = t + 512 * p;        // 0..1023
        int c = i & 63;             // column
        int kg = i >> 6;            // k-group 0..15
        float v[8];
        #pragma unroll
        for (int j = 0; j < 8; ++j)
            v[j] = W2[(kg * 8 + j) * OUT_DIM + c];
        bf16x8 w;
        #pragma unroll
        for (int j = 0; j < 8; ++j) w[j] = (__bf16)v[j];
        *(bf16x8*)&Bs[bsw2(c, kg * 8)] = w;
    }
    __syncthreads();   // only barrier

    f32x4 acc[4] = {};

    #pragma unroll
    for (int k0 = 0; k0 < HIDDEN; k0 += 32) {
        bf16x8 a = {};
        if (g < N_NODES)
            a = *(const bf16x8*)&AGG[(size_t)g * HIDDEN + k0 + q * 8];
        #pragma unroll
        for (int ni = 0; ni < 4; ++ni) {
            bf16x8 bfr = *(const bf16x8*)&Bs[bsw2(ni * 16 + lm, k0 + q * 8)];
            acc[ni] = __builtin_amdgcn_mfma_f32_16x16x32_bf16(a, bfr, acc[ni], 0, 0, 0);
        }
    }

    #pragma unroll
    for (int r = 0; r < 4; ++r) {
        int grow = row0 + wave * 16 + q * 4 + r;
        if (grow < N_NODES) {
            #pragma unroll
            for (int ni = 0; ni < 4; ++ni)
                H2[grow * OUT_DIM + ni * 16 + lm] = (__bf16)acc[ni][r];
        }
    }
}

// ---------------------------------------------------------------------------
// gather layer2: OUT[n] = relu( sum coef*H2[src] + dinv^2*H2[n] + b2 )  (f32)
// R2 form: 8 lanes x bf16x8 per node, 32 nodes/block, x4 unroll.
// ---------------------------------------------------------------------------
__launch_bounds__(256)
__global__ void k_gather2(const int* __restrict__ rowstart, const int* __restrict__ esrc,
                          const float* __restrict__ dinv,
                          const __bf16* __restrict__ H2, const float* __restrict__ b2,
                          float* __restrict__ OUT) {
    int n = blockIdx.x * 32 + (threadIdx.x >> 3);
    if (n >= N_NODES) return;
    int j = (threadIdx.x & 7) * 8;

    float dn = dinv[n];
    float s = dn * dn;
    bf16x8 h = *(const bf16x8*)&H2[n * OUT_DIM + j];
    float acc[8];
    #pragma unroll
    for (int i = 0; i < 8; ++i) acc[i] = (float)h[i] * s;

    int p0 = rowstart[n], p1 = rowstart[n + 1];
    int p = p0;
    for (; p + 3 < p1; p += 4) {
        int s0 = esrc[p + 0], s1 = esrc[p + 1], s2 = esrc[p + 2], s3 = esrc[p + 3];
        float c0 = dinv[s0] * dn, c1 = dinv[s1] * dn;
        float c2 = dinv[s2] * dn, c3 = dinv[s3] * dn;
        bf16x8 v0 = *(const bf16x8*)&H2[s0 * OUT_DIM + j];
        bf16x8 v1 = *(const bf16x8*)&H2[s1 * OUT_DIM + j];
        bf16x8 v2 = *(const bf16x8*)&H2[s2 * OUT_DIM + j];
        bf16x8 v3 = *(const bf16x8*)&H2[s3 * OUT_DIM + j];
        #pragma unroll
        for (int i = 0; i < 8; ++i) acc[i] = fmaf((float)v0[i], c0, acc[i]);
        #pragma unroll
        for (int i = 0; i < 8; ++i) acc[i] = fmaf((float)v1[i], c1, acc[i]);
        #pragma unroll
        for (int i = 0; i < 8; ++i) acc[i] = fmaf((float)v2[i], c2, acc[i]);
        #pragma unroll
        for (int i = 0; i < 8; ++i) acc[i] = fmaf((float)v3[i], c3, acc[i]);
    }
    for (; p < p1; ++p) {
        int sidx = esrc[p];
        float c = dinv[sidx] * dn;
        bf16x8 v = *(const bf16x8*)&H2[sidx * OUT_DIM + j];
        #pragma unroll
        for (int i = 0; i < 8; ++i) acc[i] = fmaf((float)v[i], c, acc[i]);
    }

    float4 bb0 = *(const float4*)&b2[j];
    float4 bb1 = *(const float4*)&b2[j + 4];
    float4 o0, o1;
    o0.x = fmaxf(acc[0] + bb0.x, 0.f);
    o0.y = fmaxf(acc[1] + bb0.y, 0.f);
    o0.z = fmaxf(acc[2] + bb0.z, 0.f);
    o0.w = fmaxf(acc[3] + bb0.w, 0.f);
    o1.x = fmaxf(acc[4] + bb1.x, 0.f);
    o1.y = fmaxf(acc[5] + bb1.y, 0.f);
    o1.z = fmaxf(acc[6] + bb1.z, 0.f);
    o1.w = fmaxf(acc[7] + bb1.w, 0.f);
    *(float4*)&OUT[n * OUT_DIM + j] = o0;
    *(float4*)&OUT[n * OUT_DIM + j + 4] = o1;
}

extern "C" void kernel_launch(void* const* d_in, const int* in_sizes, int n_in,
                              void* d_out, int out_size, void* d_ws, size_t ws_size,
                              hipStream_t stream) {
    const float* x  = (const float*)d_in[0];
    const int* ei   = (const int*)d_in[1];
    const float* W1 = (const float*)d_in[2];
    const float* b1 = (const float*)d_in[3];
    const float* W2 = (const float*)d_in[4];
    const float* b2 = (const float*)d_in[5];
    float* out = (float*)d_out;

    const int* src = ei;
    const int* dst = ei + N_EDGES;

    char* ws = (char*)d_ws;
    int*          cnt2     = (int*)         (ws + 0x000000);   // 400,384 B (becomes off2)
    int*          bsum     = (int*)         (ws + 0x080000);   // 1,564 B
    int*          rowstart = (int*)         (ws + 0x090000);   // 400,004 B
    float*        dinv     = (float*)       (ws + 0x100000);   // 400,000 B
    unsigned int* ebuf     = (unsigned int*)(ws + 0x180000);   // 6.4 MB
    int*          esrc     = (int*)         (ws + 0x800000);   // 6.4 MB
    __bf16*       h1       = (__bf16*)      (ws + 0xE80000);   // 25.6 MB
    __bf16*       agg1     = (__bf16*)      (ws + 0x2880000);  // 25.6 MB
    __bf16*       h2       = (__bf16*)      (ws + 0x4280000);  // 12.8 MB

    // CSR build with gemm1 tile-blocks distributed as passengers (gemm1 is
    // independent of the CSR chain; all 782 tiles complete by end of k_fine_g)
    k_hist_g   <<<NBLK3     + G_HIST,  512, 0, stream>>>(dst, cnt2, x, W1, h1);
    k_scan1_g  <<<NBLK_SCAN + G_SCAN1, 512, 0, stream>>>(cnt2, bsum, x, W1, h1);
    k_scan2_g  <<<1         + G_SCAN2, 512, 0, stream>>>(bsum, x, W1, h1);
    k_scatter_g<<<NBLK3     + G_SCAT,  512, 0, stream>>>(src, dst, cnt2, bsum, ebuf,
                                                         x, W1, h1);
    k_fine_g   <<<NBIN      + G_FINE,  512, 0, stream>>>(ebuf, cnt2, bsum, esrc,
                                                         rowstart, dinv, x, W1, h1);

    // layer 1 aggregation
    k_gather1<<<(N_NODES + 15) / 16, 256, 0, stream>>>(rowstart, esrc, dinv, h1, b1, agg1);
    // layer 2
    k_gemm2<<<(N_NODES + 127) / 128, 512, 0, stream>>>(agg1, W2, h2);
    k_gather2<<<(N_NODES + 31) / 32, 256, 0, stream>>>(rowstart, esrc, dinv, h2, b2, out);
}

// Round 9
// 329.520 us; speedup vs baseline: 1.0512x; 1.0132x over previous
//
#include <hip/hip_runtime.h>

#define N_NODES 100000
#define N_EDGES 1600000
#define IN_DIM 256
#define HIDDEN 128
#define OUT_DIM 64

#define NBIN 391       // coarse bins of 256 nodes: ceil(100000/256)
#define NBLK3 256      // histogram/scatter blocks
#define CHUNK 6250     // edges per block: N_EDGES / NBLK3 exactly
#define NMAT (NBIN * NBLK3)      // 100096 = scan length
#define NBLK_SCAN (NMAT / 256)   // 391 exactly
#define CAP 6144       // max edges per bin (mean 4096, sigma 64 -> 32 sigma margin)

// gemm1 passenger-tile distribution across the CSR chain (782 tiles total)
#define G1_TILES 782
#define G_HIST  160
#define G_SCAN1 120
#define G_SCAN2 60
#define G_SCAT  160
#define G_FINE  282
#define OFF_HIST  0
#define OFF_SCAN1 160
#define OFF_SCAN2 280
#define OFF_SCAT  340
#define OFF_FINE  500

// LDS index-stage capacities (mean 256 / 512 edges; >=22 sigma margin)
#define CAPL1 640
#define CAPL2 1024

typedef __bf16 bf16x8 __attribute__((ext_vector_type(8)));
typedef __bf16 bf16x4 __attribute__((ext_vector_type(4)));
typedef float f32x4 __attribute__((ext_vector_type(4)));

// ---------------------------------------------------------------------------
// GEMM1 tile as a device function (512 threads): H[bid*128..+128][128] =
// bf16(X @ W1).  W1 staged in TWO 32KB halves into Bs (swizzled b128 writes,
// coalesced reads).  A direct global->reg.
// ---------------------------------------------------------------------------
__device__ __forceinline__ int bsw1h(int c, int kk) {   // kk in [0,128)
    return c * 128 + (kk ^ ((c & 7) << 3));
}

__device__ __forceinline__ void gemm1_tile(const float* __restrict__ X,
                                           const float* __restrict__ W1,
                                           __bf16* __restrict__ H,
                                           int bid, __bf16* Bs) {
    const int t = threadIdx.x;
    const int wave = t >> 6;
    const int lane = t & 63;
    const int lm = lane & 15;
    const int q = lane >> 4;
    const int row0 = bid * 128;
    const int g = row0 + wave * 16 + lm;   // the row this lane loads

    f32x4 acc[8] = {};

    for (int half = 0; half < 2; ++half) {
        __syncthreads();   // everyone done reading previous Bs image
        for (int p = 0; p < 4; ++p) {
            int i = t + 512 * p;        // 0..2047
            int c = i & 127;            // column
            int kg = i >> 7;            // k-group 0..15
            float v[8];
            #pragma unroll
            for (int j = 0; j < 8; ++j)
                v[j] = W1[(half * 128 + kg * 8 + j) * HIDDEN + c];
            bf16x8 w;
            #pragma unroll
            for (int j = 0; j < 8; ++j) w[j] = (__bf16)v[j];
            *(bf16x8*)&Bs[bsw1h(c, kg * 8)] = w;
        }
        __syncthreads();

        #pragma unroll
        for (int k0 = 0; k0 < 128; k0 += 32) {
            float4 v0 = make_float4(0.f, 0.f, 0.f, 0.f), v1 = v0;
            if (g < N_NODES) {
                const float* p = &X[(size_t)g * IN_DIM + half * 128 + k0 + q * 8];
                v0 = *(const float4*)p;
                v1 = *(const float4*)(p + 4);
            }
            bf16x8 a;
            a[0] = (__bf16)v0.x; a[1] = (__bf16)v0.y;
            a[2] = (__bf16)v0.z; a[3] = (__bf16)v0.w;
            a[4] = (__bf16)v1.x; a[5] = (__bf16)v1.y;
            a[6] = (__bf16)v1.z; a[7] = (__bf16)v1.w;
            #pragma unroll
            for (int ni = 0; ni < 8; ++ni) {
                bf16x8 bfr = *(const bf16x8*)&Bs[bsw1h(ni * 16 + lm, k0 + q * 8)];
                acc[ni] = __builtin_amdgcn_mfma_f32_16x16x32_bf16(a, bfr, acc[ni], 0, 0, 0);
            }
        }
    }

    #pragma unroll
    for (int r = 0; r < 4; ++r) {
        int grow = row0 + wave * 16 + q * 4 + r;
        if (grow < N_NODES) {
            #pragma unroll
            for (int ni = 0; ni < 8; ++ni)
                H[grow * HIDDEN + ni * 16 + lm] = (__bf16)acc[ni][r];
        }
    }
}

// ---------------------------------------------------------------------------
// P1 + gemm passengers: per-(bin,block) histogram (blocks < NBLK3), else a
// gemm1 tile.  Branch is block-uniform -> barriers safe.
// ---------------------------------------------------------------------------
__global__ __launch_bounds__(512, 4)
void k_hist_g(const int* __restrict__ dst, int* __restrict__ cnt2,
              const float* __restrict__ X, const float* __restrict__ W1,
              __bf16* __restrict__ H) {
    __shared__ __attribute__((aligned(16))) char smem[32768];
    if (blockIdx.x < NBLK3) {
        int* hist = (int*)smem;
        int t = threadIdx.x;
        for (int i = t; i < NBIN; i += 512) hist[i] = 0;
        __syncthreads();
        int base = blockIdx.x * CHUNK;
        for (int i = t; i < CHUNK; i += 512)
            atomicAdd(&hist[dst[base + i] >> 8], 1);
        __syncthreads();
        for (int k = t; k < NBIN; k += 512)
            cnt2[k * NBLK3 + blockIdx.x] = hist[k];
    } else {
        gemm1_tile(X, W1, H, OFF_HIST + (int)blockIdx.x - NBLK3, (__bf16*)smem);
    }
}

// ---------------------------------------------------------------------------
// P2a + passengers: per-block exclusive scan (256 elems).
// ---------------------------------------------------------------------------
__global__ __launch_bounds__(512, 4)
void k_scan1_g(int* __restrict__ a, int* __restrict__ bsum,
               const float* __restrict__ X, const float* __restrict__ W1,
               __bf16* __restrict__ H) {
    __shared__ __attribute__((aligned(16))) char smem[32768];
    if (blockIdx.x < NBLK_SCAN) {
        int* tmp = (int*)smem;
        int t = threadIdx.x;
        int i = blockIdx.x * 256 + t;
        int v = 0;
        if (t < 256) { v = a[i]; tmp[t] = v; }
        __syncthreads();
        #pragma unroll
        for (int off = 1; off < 256; off <<= 1) {
            int p = (t >= off && t < 256) ? tmp[t - off] : 0;
            __syncthreads();
            if (t < 256) tmp[t] += p;
            __syncthreads();
        }
        if (t < 256) a[i] = tmp[t] - v;   // exclusive within bin-row
        if (t == 255) bsum[blockIdx.x] = tmp[255];
    } else {
        gemm1_tile(X, W1, H, OFF_SCAN1 + (int)blockIdx.x - NBLK_SCAN, (__bf16*)smem);
    }
}

// ---------------------------------------------------------------------------
// P2b + passengers: block-sum exclusive scan (single CSR block).
// ---------------------------------------------------------------------------
__global__ __launch_bounds__(512, 4)
void k_scan2_g(int* __restrict__ bsum,
               const float* __restrict__ X, const float* __restrict__ W1,
               __bf16* __restrict__ H) {
    __shared__ __attribute__((aligned(16))) char smem[32768];
    if (blockIdx.x == 0) {
        int* tmp = (int*)smem;   // 512 ints
        int t = threadIdx.x;
        int v = (t < NBLK_SCAN) ? bsum[t] : 0;
        tmp[t] = v;
        __syncthreads();
        #pragma unroll
        for (int off = 1; off < 512; off <<= 1) {
            int p = (t >= off) ? tmp[t - off] : 0;
            __syncthreads();
            tmp[t] += p;
            __syncthreads();
        }
        if (t < NBLK_SCAN) bsum[t] = tmp[t] - v;
    } else {
        gemm1_tile(X, W1, H, OFF_SCAN2 + (int)blockIdx.x - 1, (__bf16*)smem);
    }
}

// ---------------------------------------------------------------------------
// P3 + passengers: scatter edges into bin-grouped ebuf.
// ---------------------------------------------------------------------------
__global__ __launch_bounds__(512, 4)
void k_scatter_g(const int* __restrict__ src, const int* __restrict__ dst,
                 const int* __restrict__ off2, const int* __restrict__ bsum,
                 unsigned int* __restrict__ ebuf,
                 const float* __restrict__ X, const float* __restrict__ W1,
                 __bf16* __restrict__ H) {
    __shared__ __attribute__((aligned(16))) char smem[32768];
    if (blockIdx.x < NBLK3) {
        int* cursor = (int*)smem;
        int t = threadIdx.x;
        for (int k = t; k < NBIN; k += 512)
            cursor[k] = off2[k * NBLK3 + blockIdx.x] + bsum[k];
        __syncthreads();
        int base = blockIdx.x * CHUNK;
        for (int i = t; i < CHUNK; i += 512) {
            int s = src[base + i], d = dst[base + i];
            int pos = atomicAdd(&cursor[d >> 8], 1);
            ebuf[pos] = ((unsigned)s << 8) | (unsigned)(d & 255);
        }
    } else {
        gemm1_tile(X, W1, H, OFF_SCAT + (int)blockIdx.x - NBLK3, (__bf16*)smem);
    }
}

// ---------------------------------------------------------------------------
// P4 + passengers: fine counting-sort within each bin; fuses dinv + rowstart.
// ---------------------------------------------------------------------------
struct FineSm {
    int hist[256];
    int tmp[256];
    int nodeoff[256];
    int cursor[256];
    unsigned int ed[CAP];
    int sOut[CAP];
};   // 53,248 B

__global__ __launch_bounds__(512, 4)
void k_fine_g(const unsigned int* __restrict__ ebuf, const int* __restrict__ off2,
              const int* __restrict__ bsum,
              int* __restrict__ esrc, int* __restrict__ rowstart,
              float* __restrict__ dinv,
              const float* __restrict__ X, const float* __restrict__ W1,
              __bf16* __restrict__ H) {
    __shared__ __attribute__((aligned(16))) char smem[sizeof(FineSm)];
    if (blockIdx.x < NBIN) {
        FineSm* sm = (FineSm*)smem;
        const int k = blockIdx.x;
        const int t = threadIdx.x;
        const int e0 = off2[k * NBLK3] + bsum[k];
        const int e1 = (k + 1 < NBIN) ? off2[(k + 1) * NBLK3] + bsum[k + 1] : N_EDGES;
        int m = e1 - e0;
        if (m > CAP) m = CAP;  // safety clamp (statistically unreachable)

        if (t < 256) sm->hist[t] = 0;
        __syncthreads();
        for (int i = t; i < m; i += 512) {
            unsigned v = ebuf[e0 + i];
            sm->ed[i] = v;
            atomicAdd(&sm->hist[v & 255], 1);
        }
        __syncthreads();

        int v = (t < 256) ? sm->hist[t] : 0;
        if (t < 256) sm->tmp[t] = v;
        __syncthreads();
        #pragma unroll
        for (int off = 1; off < 256; off <<= 1) {
            int p = (t >= off && t < 256) ? sm->tmp[t - off] : 0;
            __syncthreads();
            if (t < 256) sm->tmp[t] += p;
            __syncthreads();
        }
        if (t < 256) {
            sm->nodeoff[t] = sm->tmp[t] - v;
            sm->cursor[t] = sm->tmp[t] - v;
        }
        __syncthreads();

        for (int i = t; i < m; i += 512) {
            unsigned e = sm->ed[i];
            int pos = atomicAdd(&sm->cursor[e & 255], 1);
            sm->sOut[pos] = (int)(e >> 8);
        }
        __syncthreads();

        for (int i = t; i < m; i += 512) esrc[e0 + i] = sm->sOut[i];

        if (t < 256) {
            int n = k * 256 + t;
            if (n < N_NODES) {
                rowstart[n] = e0 + sm->nodeoff[t];
                dinv[n] = rsqrtf((float)sm->hist[t] + 1.0f);
            }
        }
        if (k == 0 && t == 0) rowstart[N_NODES] = N_EDGES;
    } else {
        gemm1_tile(X, W1, H, OFF_FINE + (int)blockIdx.x - NBIN, (__bf16*)smem);
    }
}

// ---------------------------------------------------------------------------
// gather layer1: AGG[n] = bf16(relu( sum coef*H[src] + dinv^2*H[n] + b1 ))
// 16 lanes x bf16x8 per node, 16 nodes/block, x4 unroll.  The block's
// contiguous esrc range is STAGED IN LDS first (one coalesced pass +
// barrier) so the index fetch leaves the vmcnt dependency chain: inner
// loop reads indices via ds_read (lgkmcnt, ~120cy, prefetchable) and only
// the H/dinv gathers remain on the global-latency chain.
// Overflow (>CAPL1 edges per 16 nodes, >=22 sigma) falls back per node.
// ---------------------------------------------------------------------------
__launch_bounds__(256)
__global__ void k_gather1(const int* __restrict__ rowstart, const int* __restrict__ esrc,
                          const float* __restrict__ dinv,
                          const __bf16* __restrict__ H, const float* __restrict__ b1,
                          __bf16* __restrict__ AGG) {
    __shared__ int eidx[CAPL1];
    const int nb = blockIdx.x * 16;        // grid is exactly N_NODES/16
    const int t = threadIdx.x;
    const int e0 = rowstart[nb];
    const int m = rowstart[nb + 16] - e0;  // rowstart[N_NODES] is valid
    for (int i = t; i < m && i < CAPL1; i += 256) eidx[i] = esrc[e0 + i];
    __syncthreads();

    const int n = nb + (t >> 4);
    const int j = (t & 15) * 8;

    float dn = dinv[n];
    float s = dn * dn;
    bf16x8 h = *(const bf16x8*)&H[n * HIDDEN + j];
    float acc[8];
    #pragma unroll
    for (int i = 0; i < 8; ++i) acc[i] = (float)h[i] * s;

    int p = rowstart[n] - e0, p1 = rowstart[n + 1] - e0;
    if (p1 <= CAPL1) {
        // fast path: indices from LDS
        for (; p + 3 < p1; p += 4) {
            int s0 = eidx[p + 0], s1 = eidx[p + 1], s2 = eidx[p + 2], s3 = eidx[p + 3];
            float c0 = dinv[s0] * dn, c1 = dinv[s1] * dn;
            float c2 = dinv[s2] * dn, c3 = dinv[s3] * dn;
            bf16x8 v0 = *(const bf16x8*)&H[s0 * HIDDEN + j];
            bf16x8 v1 = *(const bf16x8*)&H[s1 * HIDDEN + j];
            bf16x8 v2 = *(const bf16x8*)&H[s2 * HIDDEN + j];
            bf16x8 v3 = *(const bf16x8*)&H[s3 * HIDDEN + j];
            #pragma unroll
            for (int i = 0; i < 8; ++i) acc[i] = fmaf((float)v0[i], c0, acc[i]);
            #pragma unroll
            for (int i = 0; i < 8; ++i) acc[i] = fmaf((float)v1[i], c1, acc[i]);
            #pragma unroll
            for (int i = 0; i < 8; ++i) acc[i] = fmaf((float)v2[i], c2, acc[i]);
            #pragma unroll
            for (int i = 0; i < 8; ++i) acc[i] = fmaf((float)v3[i], c3, acc[i]);
        }
        for (; p < p1; ++p) {
            int sidx = eidx[p];
            float c = dinv[sidx] * dn;
            bf16x8 v = *(const bf16x8*)&H[sidx * HIDDEN + j];
            #pragma unroll
            for (int i = 0; i < 8; ++i) acc[i] = fmaf((float)v[i], c, acc[i]);
        }
    } else {
        // fallback: original global path (statistically near-never)
        const int* ep = esrc + e0;
        for (; p + 3 < p1; p += 4) {
            int s0 = ep[p + 0], s1 = ep[p + 1], s2 = ep[p + 2], s3 = ep[p + 3];
            float c0 = dinv[s0] * dn, c1 = dinv[s1] * dn;
            float c2 = dinv[s2] * dn, c3 = dinv[s3] * dn;
            bf16x8 v0 = *(const bf16x8*)&H[s0 * HIDDEN + j];
            bf16x8 v1 = *(const bf16x8*)&H[s1 * HIDDEN + j];
            bf16x8 v2 = *(const bf16x8*)&H[s2 * HIDDEN + j];
            bf16x8 v3 = *(const bf16x8*)&H[s3 * HIDDEN + j];
            #pragma unroll
            for (int i = 0; i < 8; ++i) acc[i] = fmaf((float)v0[i], c0, acc[i]);
            #pragma unroll
            for (int i = 0; i < 8; ++i) acc[i] = fmaf((float)v1[i], c1, acc[i]);
            #pragma unroll
            for (int i = 0; i < 8; ++i) acc[i] = fmaf((float)v2[i], c2, acc[i]);
            #pragma unroll
            for (int i = 0; i < 8; ++i) acc[i] = fmaf((float)v3[i], c3, acc[i]);
        }
        for (; p < p1; ++p) {
            int sidx = ep[p];
            float c = dinv[sidx] * dn;
            bf16x8 v = *(const bf16x8*)&H[sidx * HIDDEN + j];
            #pragma unroll
            for (int i = 0; i < 8; ++i) acc[i] = fmaf((float)v[i], c, acc[i]);
        }
    }

    float4 bb0 = *(const float4*)&b1[j];
    float4 bb1 = *(const float4*)&b1[j + 4];
    bf16x8 o;
    o[0] = (__bf16)fmaxf(acc[0] + bb0.x, 0.f);
    o[1] = (__bf16)fmaxf(acc[1] + bb0.y, 0.f);
    o[2] = (__bf16)fmaxf(acc[2] + bb0.z, 0.f);
    o[3] = (__bf16)fmaxf(acc[3] + bb0.w, 0.f);
    o[4] = (__bf16)fmaxf(acc[4] + bb1.x, 0.f);
    o[5] = (__bf16)fmaxf(acc[5] + bb1.y, 0.f);
    o[6] = (__bf16)fmaxf(acc[6] + bb1.z, 0.f);
    o[7] = (__bf16)fmaxf(acc[7] + bb1.w, 0.f);
    *(bf16x8*)&AGG[n * HIDDEN + j] = o;
}

// ---------------------------------------------------------------------------
// GEMM2 (bf16 MFMA): H2[M][64] = AGG[M][128] @ bf16(W2[128][64])
// R6 form: 128 rows/block, grid 782, LDS 16KB, (512,8).
// ---------------------------------------------------------------------------
__device__ __forceinline__ int bsw2(int c, int kk) {
    return c * 128 + (kk ^ ((c & 7) << 3));
}

__launch_bounds__(512, 8)
__global__ void k_gemm2(const __bf16* __restrict__ AGG, const float* __restrict__ W2,
                        __bf16* __restrict__ H2) {
    __shared__ __attribute__((aligned(16))) __bf16 Bs[64 * 128];  // 16 KB

    const int t = threadIdx.x;
    const int wave = t >> 6;
    const int lane = t & 63;
    const int lm = lane & 15;
    const int q = lane >> 4;
    const int row0 = blockIdx.x * 128;
    const int g = row0 + wave * 16 + lm;

    for (int p = 0; p < 2; ++p) {
        int i = t + 512 * p;        // 0..1023
        int c = i & 63;             // column
        int kg = i >> 6;            // k-group 0..15
        float v[8];
        #pragma unroll
        for (int j = 0; j < 8; ++j)
            v[j] = W2[(kg * 8 + j) * OUT_DIM + c];
        bf16x8 w;
        #pragma unroll
        for (int j = 0; j < 8; ++j) w[j] = (__bf16)v[j];
        *(bf16x8*)&Bs[bsw2(c, kg * 8)] = w;
    }
    __syncthreads();   // only barrier

    f32x4 acc[4] = {};

    #pragma unroll
    for (int k0 = 0; k0 < HIDDEN; k0 += 32) {
        bf16x8 a = {};
        if (g < N_NODES)
            a = *(const bf16x8*)&AGG[(size_t)g * HIDDEN + k0 + q * 8];
        #pragma unroll
        for (int ni = 0; ni < 4; ++ni) {
            bf16x8 bfr = *(const bf16x8*)&Bs[bsw2(ni * 16 + lm, k0 + q * 8)];
            acc[ni] = __builtin_amdgcn_mfma_f32_16x16x32_bf16(a, bfr, acc[ni], 0, 0, 0);
        }
    }

    #pragma unroll
    for (int r = 0; r < 4; ++r) {
        int grow = row0 + wave * 16 + q * 4 + r;
        if (grow < N_NODES) {
            #pragma unroll
            for (int ni = 0; ni < 4; ++ni)
                H2[grow * OUT_DIM + ni * 16 + lm] = (__bf16)acc[ni][r];
        }
    }
}

// ---------------------------------------------------------------------------
// gather layer2: OUT[n] = relu( sum coef*H2[src] + dinv^2*H2[n] + b2 )  (f32)
// 8 lanes x bf16x8 per node, 32 nodes/block, x4 unroll; LDS index staging
// as in k_gather1 (CAPL2 = 1024 for 32 nodes).
// ---------------------------------------------------------------------------
__launch_bounds__(256)
__global__ void k_gather2(const int* __restrict__ rowstart, const int* __restrict__ esrc,
                          const float* __restrict__ dinv,
                          const __bf16* __restrict__ H2, const float* __restrict__ b2,
                          float* __restrict__ OUT) {
    __shared__ int eidx[CAPL2];
    const int nb = blockIdx.x * 32;        // grid is exactly N_NODES/32
    const int t = threadIdx.x;
    const int e0 = rowstart[nb];
    const int m = rowstart[nb + 32] - e0;
    for (int i = t; i < m && i < CAPL2; i += 256) eidx[i] = esrc[e0 + i];
    __syncthreads();

    const int n = nb + (t >> 3);
    const int j = (t & 7) * 8;

    float dn = dinv[n];
    float s = dn * dn;
    bf16x8 h = *(const bf16x8*)&H2[n * OUT_DIM + j];
    float acc[8];
    #pragma unroll
    for (int i = 0; i < 8; ++i) acc[i] = (float)h[i] * s;

    int p = rowstart[n] - e0, p1 = rowstart[n + 1] - e0;
    if (p1 <= CAPL2) {
        for (; p + 3 < p1; p += 4) {
            int s0 = eidx[p + 0], s1 = eidx[p + 1], s2 = eidx[p + 2], s3 = eidx[p + 3];
            float c0 = dinv[s0] * dn, c1 = dinv[s1] * dn;
            float c2 = dinv[s2] * dn, c3 = dinv[s3] * dn;
            bf16x8 v0 = *(const bf16x8*)&H2[s0 * OUT_DIM + j];
            bf16x8 v1 = *(const bf16x8*)&H2[s1 * OUT_DIM + j];
            bf16x8 v2 = *(const bf16x8*)&H2[s2 * OUT_DIM + j];
            bf16x8 v3 = *(const bf16x8*)&H2[s3 * OUT_DIM + j];
            #pragma unroll
            for (int i = 0; i < 8; ++i) acc[i] = fmaf((float)v0[i], c0, acc[i]);
            #pragma unroll
            for (int i = 0; i < 8; ++i) acc[i] = fmaf((float)v1[i], c1, acc[i]);
            #pragma unroll
            for (int i = 0; i < 8; ++i) acc[i] = fmaf((float)v2[i], c2, acc[i]);
            #pragma unroll
            for (int i = 0; i < 8; ++i) acc[i] = fmaf((float)v3[i], c3, acc[i]);
        }
        for (; p < p1; ++p) {
            int sidx = eidx[p];
            float c = dinv[sidx] * dn;
            bf16x8 v = *(const bf16x8*)&H2[sidx * OUT_DIM + j];
            #pragma unroll
            for (int i = 0; i < 8; ++i) acc[i] = fmaf((float)v[i], c, acc[i]);
        }
    } else {
        const int* ep = esrc + e0;
        for (; p + 3 < p1; p += 4) {
            int s0 = ep[p + 0], s1 = ep[p + 1], s2 = ep[p + 2], s3 = ep[p + 3];
            float c0 = dinv[s0] * dn, c1 = dinv[s1] * dn;
            float c2 = dinv[s2] * dn, c3 = dinv[s3] * dn;
            bf16x8 v0 = *(const bf16x8*)&H2[s0 * OUT_DIM + j];
            bf16x8 v1 = *(const bf16x8*)&H2[s1 * OUT_DIM + j];
            bf16x8 v2 = *(const bf16x8*)&H2[s2 * OUT_DIM + j];
            bf16x8 v3 = *(const bf16x8*)&H2[s3 * OUT_DIM + j];
            #pragma unroll
            for (int i = 0; i < 8; ++i) acc[i] = fmaf((float)v0[i], c0, acc[i]);
            #pragma unroll
            for (int i = 0; i < 8; ++i) acc[i] = fmaf((float)v1[i], c1, acc[i]);
            #pragma unroll
            for (int i = 0; i < 8; ++i) acc[i] = fmaf((float)v2[i], c2, acc[i]);
            #pragma unroll
            for (int i = 0; i < 8; ++i) acc[i] = fmaf((float)v3[i], c3, acc[i]);
        }
        for (; p < p1; ++p) {
            int sidx = ep[p];
            float c = dinv[sidx] * dn;
            bf16x8 v = *(const bf16x8*)&H2[sidx * OUT_DIM + j];
            #pragma unroll
            for (int i = 0; i < 8; ++i) acc[i] = fmaf((float)v[i], c, acc[i]);
        }
    }

    float4 bb0 = *(const float4*)&b2[j];
    float4 bb1 = *(const float4*)&b2[j + 4];
    float4 o0, o1;
    o0.x = fmaxf(acc[0] + bb0.x, 0.f);
    o0.y = fmaxf(acc[1] + bb0.y, 0.f);
    o0.z = fmaxf(acc[2] + bb0.z, 0.f);
    o0.w = fmaxf(acc[3] + bb0.w, 0.f);
    o1.x = fmaxf(acc[4] + bb1.x, 0.f);
    o1.y = fmaxf(acc[5] + bb1.y, 0.f);
    o1.z = fmaxf(acc[6] + bb1.z, 0.f);
    o1.w = fmaxf(acc[7] + bb1.w, 0.f);
    *(float4*)&OUT[n * OUT_DIM + j] = o0;
    *(float4*)&OUT[n * OUT_DIM + j + 4] = o1;
}

extern "C" void kernel_launch(void* const* d_in, const int* in_sizes, int n_in,
                              void* d_out, int out_size, void* d_ws, size_t ws_size,
                              hipStream_t stream) {
    const float* x  = (const float*)d_in[0];
    const int* ei   = (const int*)d_in[1];
    const float* W1 = (const float*)d_in[2];
    const float* b1 = (const float*)d_in[3];
    const float* W2 = (const float*)d_in[4];
    const float* b2 = (const float*)d_in[5];
    float* out = (float*)d_out;

    const int* src = ei;
    const int* dst = ei + N_EDGES;

    char* ws = (char*)d_ws;
    int*          cnt2     = (int*)         (ws + 0x000000);   // 400,384 B (becomes off2)
    int*          bsum     = (int*)         (ws + 0x080000);   // 1,564 B
    int*          rowstart = (int*)         (ws + 0x090000);   // 400,004 B
    float*        dinv     = (float*)       (ws + 0x100000);   // 400,000 B
    unsigned int* ebuf     = (unsigned int*)(ws + 0x180000);   // 6.4 MB
    int*          esrc     = (int*)         (ws + 0x800000);   // 6.4 MB
    __bf16*       h1       = (__bf16*)      (ws + 0xE80000);   // 25.6 MB
    __bf16*       agg1     = (__bf16*)      (ws + 0x2880000);  // 25.6 MB
    __bf16*       h2       = (__bf16*)      (ws + 0x4280000);  // 12.8 MB

    // CSR build with gemm1 tile-blocks distributed as passengers
    k_hist_g   <<<NBLK3     + G_HIST,  512, 0, stream>>>(dst, cnt2, x, W1, h1);
    k_scan1_g  <<<NBLK_SCAN + G_SCAN1, 512, 0, stream>>>(cnt2, bsum, x, W1, h1);
    k_scan2_g  <<<1         + G_SCAN2, 512, 0, stream>>>(bsum, x, W1, h1);
    k_scatter_g<<<NBLK3     + G_SCAT,  512, 0, stream>>>(src, dst, cnt2, bsum, ebuf,
                                                         x, W1, h1);
    k_fine_g   <<<NBIN      + G_FINE,  512, 0, stream>>>(ebuf, cnt2, bsum, esrc,
                                                         rowstart, dinv, x, W1, h1);

    // layer 1 aggregation
    k_gather1<<<N_NODES / 16, 256, 0, stream>>>(rowstart, esrc, dinv, h1, b1, agg1);
    // layer 2
    k_gemm2<<<(N_NODES + 127) / 128, 512, 0, stream>>>(agg1, W2, h2);
    k_gather2<<<N_NODES / 32, 256, 0, stream>>>(rowstart, esrc, dinv, h2, b2, out);
}

// Round 11
// 320.708 us; speedup vs baseline: 1.0801x; 1.0275x over previous
//
#include <hip/hip_runtime.h>

#define N_NODES 100000
#define N_EDGES 1600000
#define IN_DIM 256
#define HIDDEN 128
#define OUT_DIM 64

#define NBIN 391       // coarse bins of 256 nodes: ceil(100000/256)
#define NBLK3 256      // histogram/scatter blocks
#define CHUNK 6250     // edges per block: N_EDGES / NBLK3 exactly
#define NMAT (NBIN * NBLK3)      // 100096 = scan length
#define NBLK_SCAN (NMAT / 256)   // 391 exactly
#define CAP 6144       // max edges per bin (mean 4096, sigma 64 -> 32 sigma margin)

// gemm1 passenger-tile distribution across the CSR chain (782 tiles total)
#define G1_TILES 782
#define G_HIST  160
#define G_SCAN1 120
#define G_SCAN2 60
#define G_SCAT  160
#define G_FINE  282
#define OFF_HIST  0
#define OFF_SCAN1 160
#define OFF_SCAN2 280
#define OFF_SCAT  340
#define OFF_FINE  500

// LDS index-stage capacities (mean 256 / 512 edges; >=22 sigma margin)
#define CAPL1 640
#define CAPL2 1024

typedef __bf16 bf16x8 __attribute__((ext_vector_type(8)));
typedef __bf16 bf16x4 __attribute__((ext_vector_type(4)));
typedef float f32x4 __attribute__((ext_vector_type(4)));

// ---------------------------------------------------------------------------
// GEMM1 tile as a device function (512 threads): H[bid*128..+128][128] =
// bf16(X @ W1).  W1 staged in TWO 32KB halves into Bs (swizzled b128 writes,
// coalesced reads).  A direct global->reg.
// ---------------------------------------------------------------------------
__device__ __forceinline__ int bsw1h(int c, int kk) {   // kk in [0,128)
    return c * 128 + (kk ^ ((c & 7) << 3));
}

__device__ __forceinline__ void gemm1_tile(const float* __restrict__ X,
                                           const float* __restrict__ W1,
                                           __bf16* __restrict__ H,
                                           int bid, __bf16* Bs) {
    const int t = threadIdx.x;
    const int wave = t >> 6;
    const int lane = t & 63;
    const int lm = lane & 15;
    const int q = lane >> 4;
    const int row0 = bid * 128;
    const int g = row0 + wave * 16 + lm;   // the row this lane loads

    f32x4 acc[8] = {};

    for (int half = 0; half < 2; ++half) {
        __syncthreads();   // everyone done reading previous Bs image
        for (int p = 0; p < 4; ++p) {
            int i = t + 512 * p;        // 0..2047
            int c = i & 127;            // column
            int kg = i >> 7;            // k-group 0..15
            float v[8];
            #pragma unroll
            for (int j = 0; j < 8; ++j)
                v[j] = W1[(half * 128 + kg * 8 + j) * HIDDEN + c];
            bf16x8 w;
            #pragma unroll
            for (int j = 0; j < 8; ++j) w[j] = (__bf16)v[j];
            *(bf16x8*)&Bs[bsw1h(c, kg * 8)] = w;
        }
        __syncthreads();

        #pragma unroll
        for (int k0 = 0; k0 < 128; k0 += 32) {
            float4 v0 = make_float4(0.f, 0.f, 0.f, 0.f), v1 = v0;
            if (g < N_NODES) {
                const float* p = &X[(size_t)g * IN_DIM + half * 128 + k0 + q * 8];
                v0 = *(const float4*)p;
                v1 = *(const float4*)(p + 4);
            }
            bf16x8 a;
            a[0] = (__bf16)v0.x; a[1] = (__bf16)v0.y;
            a[2] = (__bf16)v0.z; a[3] = (__bf16)v0.w;
            a[4] = (__bf16)v1.x; a[5] = (__bf16)v1.y;
            a[6] = (__bf16)v1.z; a[7] = (__bf16)v1.w;
            #pragma unroll
            for (int ni = 0; ni < 8; ++ni) {
                bf16x8 bfr = *(const bf16x8*)&Bs[bsw1h(ni * 16 + lm, k0 + q * 8)];
                acc[ni] = __builtin_amdgcn_mfma_f32_16x16x32_bf16(a, bfr, acc[ni], 0, 0, 0);
            }
        }
    }

    #pragma unroll
    for (int r = 0; r < 4; ++r) {
        int grow = row0 + wave * 16 + q * 4 + r;
        if (grow < N_NODES) {
            #pragma unroll
            for (int ni = 0; ni < 8; ++ni)
                H[grow * HIDDEN + ni * 16 + lm] = (__bf16)acc[ni][r];
        }
    }
}

// ---------------------------------------------------------------------------
// P1 + gemm passengers: per-(bin,block) histogram (blocks < NBLK3), else a
// gemm1 tile.  Branch is block-uniform -> barriers safe.
// ---------------------------------------------------------------------------
__global__ __launch_bounds__(512, 4)
void k_hist_g(const int* __restrict__ dst, int* __restrict__ cnt2,
              const float* __restrict__ X, const float* __restrict__ W1,
              __bf16* __restrict__ H) {
    __shared__ __attribute__((aligned(16))) char smem[32768];
    if (blockIdx.x < NBLK3) {
        int* hist = (int*)smem;
        int t = threadIdx.x;
        for (int i = t; i < NBIN; i += 512) hist[i] = 0;
        __syncthreads();
        int base = blockIdx.x * CHUNK;
        for (int i = t; i < CHUNK; i += 512)
            atomicAdd(&hist[dst[base + i] >> 8], 1);
        __syncthreads();
        for (int k = t; k < NBIN; k += 512)
            cnt2[k * NBLK3 + blockIdx.x] = hist[k];
    } else {
        gemm1_tile(X, W1, H, OFF_HIST + (int)blockIdx.x - NBLK3, (__bf16*)smem);
    }
}

// ---------------------------------------------------------------------------
// P2a + passengers: per-block exclusive scan (256 elems).
// ---------------------------------------------------------------------------
__global__ __launch_bounds__(512, 4)
void k_scan1_g(int* __restrict__ a, int* __restrict__ bsum,
               const float* __restrict__ X, const float* __restrict__ W1,
               __bf16* __restrict__ H) {
    __shared__ __attribute__((aligned(16))) char smem[32768];
    if (blockIdx.x < NBLK_SCAN) {
        int* tmp = (int*)smem;
        int t = threadIdx.x;
        int i = blockIdx.x * 256 + t;
        int v = 0;
        if (t < 256) { v = a[i]; tmp[t] = v; }
        __syncthreads();
        #pragma unroll
        for (int off = 1; off < 256; off <<= 1) {
            int p = (t >= off && t < 256) ? tmp[t - off] : 0;
            __syncthreads();
            if (t < 256) tmp[t] += p;
            __syncthreads();
        }
        if (t < 256) a[i] = tmp[t] - v;   // exclusive within bin-row
        if (t == 255) bsum[blockIdx.x] = tmp[255];
    } else {
        gemm1_tile(X, W1, H, OFF_SCAN1 + (int)blockIdx.x - NBLK_SCAN, (__bf16*)smem);
    }
}

// ---------------------------------------------------------------------------
// P2b + passengers: block-sum exclusive scan (single CSR block).
// ---------------------------------------------------------------------------
__global__ __launch_bounds__(512, 4)
void k_scan2_g(int* __restrict__ bsum,
               const float* __restrict__ X, const float* __restrict__ W1,
               __bf16* __restrict__ H) {
    __shared__ __attribute__((aligned(16))) char smem[32768];
    if (blockIdx.x == 0) {
        int* tmp = (int*)smem;   // 512 ints
        int t = threadIdx.x;
        int v = (t < NBLK_SCAN) ? bsum[t] : 0;
        tmp[t] = v;
        __syncthreads();
        #pragma unroll
        for (int off = 1; off < 512; off <<= 1) {
            int p = (t >= off) ? tmp[t - off] : 0;
            __syncthreads();
            tmp[t] += p;
            __syncthreads();
        }
        if (t < NBLK_SCAN) bsum[t] = tmp[t] - v;
    } else {
        gemm1_tile(X, W1, H, OFF_SCAN2 + (int)blockIdx.x - 1, (__bf16*)smem);
    }
}

// ---------------------------------------------------------------------------
// P3 + passengers: scatter edges into bin-grouped ebuf.
// ---------------------------------------------------------------------------
__global__ __launch_bounds__(512, 4)
void k_scatter_g(const int* __restrict__ src, const int* __restrict__ dst,
                 const int* __restrict__ off2, const int* __restrict__ bsum,
                 unsigned int* __restrict__ ebuf,
                 const float* __restrict__ X, const float* __restrict__ W1,
                 __bf16* __restrict__ H) {
    __shared__ __attribute__((aligned(16))) char smem[32768];
    if (blockIdx.x < NBLK3) {
        int* cursor = (int*)smem;
        int t = threadIdx.x;
        for (int k = t; k < NBIN; k += 512)
            cursor[k] = off2[k * NBLK3 + blockIdx.x] + bsum[k];
        __syncthreads();
        int base = blockIdx.x * CHUNK;
        for (int i = t; i < CHUNK; i += 512) {
            int s = src[base + i], d = dst[base + i];
            int pos = atomicAdd(&cursor[d >> 8], 1);
            ebuf[pos] = ((unsigned)s << 8) | (unsigned)(d & 255);
        }
    } else {
        gemm1_tile(X, W1, H, OFF_SCAT + (int)blockIdx.x - NBLK3, (__bf16*)smem);
    }
}

// ---------------------------------------------------------------------------
// P4 + passengers: fine counting-sort within each bin; fuses dinv + rowstart.
// ---------------------------------------------------------------------------
struct FineSm {
    int hist[256];
    int tmp[256];
    int nodeoff[256];
    int cursor[256];
    unsigned int ed[CAP];
    int sOut[CAP];
};   // 53,248 B

__global__ __launch_bounds__(512, 4)
void k_fine_g(const unsigned int* __restrict__ ebuf, const int* __restrict__ off2,
              const int* __restrict__ bsum,
              int* __restrict__ esrc, int* __restrict__ rowstart,
              float* __restrict__ dinv,
              const float* __restrict__ X, const float* __restrict__ W1,
              __bf16* __restrict__ H) {
    __shared__ __attribute__((aligned(16))) char smem[sizeof(FineSm)];
    if (blockIdx.x < NBIN) {
        FineSm* sm = (FineSm*)smem;
        const int k = blockIdx.x;
        const int t = threadIdx.x;
        const int e0 = off2[k * NBLK3] + bsum[k];
        const int e1 = (k + 1 < NBIN) ? off2[(k + 1) * NBLK3] + bsum[k + 1] : N_EDGES;
        int m = e1 - e0;
        if (m > CAP) m = CAP;  // safety clamp (statistically unreachable)

        if (t < 256) sm->hist[t] = 0;
        __syncthreads();
        for (int i = t; i < m; i += 512) {
            unsigned v = ebuf[e0 + i];
            sm->ed[i] = v;
            atomicAdd(&sm->hist[v & 255], 1);
        }
        __syncthreads();

        int v = (t < 256) ? sm->hist[t] : 0;
        if (t < 256) sm->tmp[t] = v;
        __syncthreads();
        #pragma unroll
        for (int off = 1; off < 256; off <<= 1) {
            int p = (t >= off && t < 256) ? sm->tmp[t - off] : 0;
            __syncthreads();
            if (t < 256) sm->tmp[t] += p;
            __syncthreads();
        }
        if (t < 256) {
            sm->nodeoff[t] = sm->tmp[t] - v;
            sm->cursor[t] = sm->tmp[t] - v;
        }
        __syncthreads();

        for (int i = t; i < m; i += 512) {
            unsigned e = sm->ed[i];
            int pos = atomicAdd(&sm->cursor[e & 255], 1);
            sm->sOut[pos] = (int)(e >> 8);
        }
        __syncthreads();

        for (int i = t; i < m; i += 512) esrc[e0 + i] = sm->sOut[i];

        if (t < 256) {
            int n = k * 256 + t;
            if (n < N_NODES) {
                rowstart[n] = e0 + sm->nodeoff[t];
                dinv[n] = rsqrtf((float)sm->hist[t] + 1.0f);
            }
        }
        if (k == 0 && t == 0) rowstart[N_NODES] = N_EDGES;
    } else {
        gemm1_tile(X, W1, H, OFF_FINE + (int)blockIdx.x - NBIN, (__bf16*)smem);
    }
}

// ---------------------------------------------------------------------------
// FUSED gather1 + gemm2, SAME SHAPE as the proven 60us gather1:
// grid 6250 x 256, 16 nodes/block, 16 lanes/node, one gather pass/thread,
// LDS-staged esrc indices.  The 16 agg rows go to a 4KB LDS tile (chunk-XOR
// swizzle) instead of HBM; after ONE barrier each of the 4 waves runs 4
// MFMAs (its 16-col quarter of the 16x64 H2 tile).  W2 staged per block
// (L2-hot, ~6us chip-wide, hidden under gather latency).
// AGG never touches HBM (-51.2 MB round trip, -1 dispatch).  Numerics:
// agg bf16-rounded at the same point, same MFMA k-order as k_gemm2 ->
// bit-identical.
// ---------------------------------------------------------------------------
__device__ __forceinline__ int bsw2(int c, int kk) {
    return c * 128 + (kk ^ ((c & 7) << 3));
}

__launch_bounds__(256)
__global__ void k_gather1f(const int* __restrict__ rowstart, const int* __restrict__ esrc,
                           const float* __restrict__ dinv,
                           const __bf16* __restrict__ H, const float* __restrict__ b1,
                           const float* __restrict__ W2,
                           __bf16* __restrict__ H2) {
    __shared__ int eidx[CAPL1];                                    // 2.5 KB
    __shared__ __attribute__((aligned(16))) __bf16 As[16 * 128];   // 4 KB agg tile
    __shared__ __attribute__((aligned(16))) __bf16 Bs[64 * 128];   // 16 KB W2

    const int t = threadIdx.x;
    const int nb = blockIdx.x * 16;        // grid is exactly N_NODES/16
    const int e0 = rowstart[nb];
    const int m = rowstart[nb + 16] - e0;  // rowstart[N_NODES] is valid

    // stage W2 -> Bs bf16 [col][k] swizzled (b128 writes, coalesced reads)
    #pragma unroll
    for (int p = 0; p < 4; ++p) {
        int i = t + 256 * p;        // 0..1023
        int c = i & 63;             // column
        int kg = i >> 6;            // k-group 0..15
        float v[8];
        #pragma unroll
        for (int jj = 0; jj < 8; ++jj)
            v[jj] = W2[(kg * 8 + jj) * OUT_DIM + c];
        bf16x8 w;
        #pragma unroll
        for (int jj = 0; jj < 8; ++jj) w[jj] = (__bf16)v[jj];
        *(bf16x8*)&Bs[bsw2(c, kg * 8)] = w;
    }
    // stage this block's esrc range
    for (int i = t; i < m && i < CAPL1; i += 256) eidx[i] = esrc[e0 + i];
    __syncthreads();

    const int nl = t >> 4;         // local node 0..15
    const int n = nb + nl;
    const int jc = t & 15;         // 16B chunk index within row
    const int j = jc * 8;          // feature offset

    float dn = dinv[n];
    float s = dn * dn;
    bf16x8 h = *(const bf16x8*)&H[n * HIDDEN + j];
    float acc[8];
    #pragma unroll
    for (int i = 0; i < 8; ++i) acc[i] = (float)h[i] * s;

    int p = rowstart[n] - e0, p1 = rowstart[n + 1] - e0;
    if (p1 <= CAPL1) {
        // fast path: indices from LDS
        for (; p + 3 < p1; p += 4) {
            int s0 = eidx[p + 0], s1 = eidx[p + 1], s2 = eidx[p + 2], s3 = eidx[p + 3];
            float c0 = dinv[s0] * dn, c1 = dinv[s1] * dn;
            float c2 = dinv[s2] * dn, c3 = dinv[s3] * dn;
            bf16x8 v0 = *(const bf16x8*)&H[s0 * HIDDEN + j];
            bf16x8 v1 = *(const bf16x8*)&H[s1 * HIDDEN + j];
            bf16x8 v2 = *(const bf16x8*)&H[s2 * HIDDEN + j];
            bf16x8 v3 = *(const bf16x8*)&H[s3 * HIDDEN + j];
            #pragma unroll
            for (int i = 0; i < 8; ++i) acc[i] = fmaf((float)v0[i], c0, acc[i]);
            #pragma unroll
            for (int i = 0; i < 8; ++i) acc[i] = fmaf((float)v1[i], c1, acc[i]);
            #pragma unroll
            for (int i = 0; i < 8; ++i) acc[i] = fmaf((float)v2[i], c2, acc[i]);
            #pragma unroll
            for (int i = 0; i < 8; ++i) acc[i] = fmaf((float)v3[i], c3, acc[i]);
        }
        for (; p < p1; ++p) {
            int sidx = eidx[p];
            float c = dinv[sidx] * dn;
            bf16x8 v = *(const bf16x8*)&H[sidx * HIDDEN + j];
            #pragma unroll
            for (int i = 0; i < 8; ++i) acc[i] = fmaf((float)v[i], c, acc[i]);
        }
    } else {
        // fallback: global indices (statistically near-never)
        const int* ep = esrc + e0;
        for (; p + 3 < p1; p += 4) {
            int s0 = ep[p + 0], s1 = ep[p + 1], s2 = ep[p + 2], s3 = ep[p + 3];
            float c0 = dinv[s0] * dn, c1 = dinv[s1] * dn;
            float c2 = dinv[s2] * dn, c3 = dinv[s3] * dn;
            bf16x8 v0 = *(const bf16x8*)&H[s0 * HIDDEN + j];
            bf16x8 v1 = *(const bf16x8*)&H[s1 * HIDDEN + j];
            bf16x8 v2 = *(const bf16x8*)&H[s2 * HIDDEN + j];
            bf16x8 v3 = *(const bf16x8*)&H[s3 * HIDDEN + j];
            #pragma unroll
            for (int i = 0; i < 8; ++i) acc[i] = fmaf((float)v0[i], c0, acc[i]);
            #pragma unroll
            for (int i = 0; i < 8; ++i) acc[i] = fmaf((float)v1[i], c1, acc[i]);
            #pragma unroll
            for (int i = 0; i < 8; ++i) acc[i] = fmaf((float)v2[i], c2, acc[i]);
            #pragma unroll
            for (int i = 0; i < 8; ++i) acc[i] = fmaf((float)v3[i], c3, acc[i]);
        }
        for (; p < p1; ++p) {
            int sidx = ep[p];
            float c = dinv[sidx] * dn;
            bf16x8 v = *(const bf16x8*)&H[sidx * HIDDEN + j];
            #pragma unroll
            for (int i = 0; i < 8; ++i) acc[i] = fmaf((float)v[i], c, acc[i]);
        }
    }

    float4 bb0 = *(const float4*)&b1[j];
    float4 bb1 = *(const float4*)&b1[j + 4];
    bf16x8 o;
    o[0] = (__bf16)fmaxf(acc[0] + bb0.x, 0.f);
    o[1] = (__bf16)fmaxf(acc[1] + bb0.y, 0.f);
    o[2] = (__bf16)fmaxf(acc[2] + bb0.z, 0.f);
    o[3] = (__bf16)fmaxf(acc[3] + bb0.w, 0.f);
    o[4] = (__bf16)fmaxf(acc[4] + bb1.x, 0.f);
    o[5] = (__bf16)fmaxf(acc[5] + bb1.y, 0.f);
    o[6] = (__bf16)fmaxf(acc[6] + bb1.z, 0.f);
    o[7] = (__bf16)fmaxf(acc[7] + bb1.w, 0.f);
    // agg row -> LDS tile, chunk-XOR swizzle within the row (bijective)
    *(bf16x8*)&As[nl * 128 + (jc ^ (nl & 7)) * 8] = o;
    __syncthreads();

    // MFMA phase: wave w computes the 16-col quarter ni = w of the
    // 16x64 H2 tile (4 k-steps, same k-order as the split k_gemm2).
    const int wave = t >> 6;
    const int lane = t & 63;
    const int lm = lane & 15;
    const int q = lane >> 4;

    f32x4 acc2 = {};
    #pragma unroll
    for (int k0 = 0; k0 < HIDDEN; k0 += 32) {
        int c = (k0 >> 3) + q;     // chunk 0..15
        bf16x8 a = *(const bf16x8*)&As[lm * 128 + (c ^ (lm & 7)) * 8];
        bf16x8 bfr = *(const bf16x8*)&Bs[bsw2(wave * 16 + lm, k0 + q * 8)];
        acc2 = __builtin_amdgcn_mfma_f32_16x16x32_bf16(a, bfr, acc2, 0, 0, 0);
    }
    #pragma unroll
    for (int r = 0; r < 4; ++r)
        H2[(nb + q * 4 + r) * OUT_DIM + wave * 16 + lm] = (__bf16)acc2[r];
}

// ---------------------------------------------------------------------------
// gather layer2: OUT[n] = relu( sum coef*H2[src] + dinv^2*H2[n] + b2 )  (f32)
// 8 lanes x bf16x8 per node, 32 nodes/block, x4 unroll; LDS index staging.
// ---------------------------------------------------------------------------
__launch_bounds__(256)
__global__ void k_gather2(const int* __restrict__ rowstart, const int* __restrict__ esrc,
                          const float* __restrict__ dinv,
                          const __bf16* __restrict__ H2, const float* __restrict__ b2,
                          float* __restrict__ OUT) {
    __shared__ int eidx[CAPL2];
    const int nb = blockIdx.x * 32;        // grid is exactly N_NODES/32
    const int t = threadIdx.x;
    const int e0 = rowstart[nb];
    const int m = rowstart[nb + 32] - e0;
    for (int i = t; i < m && i < CAPL2; i += 256) eidx[i] = esrc[e0 + i];
    __syncthreads();

    const int n = nb + (t >> 3);
    const int j = (t & 7) * 8;

    float dn = dinv[n];
    float s = dn * dn;
    bf16x8 h = *(const bf16x8*)&H2[n * OUT_DIM + j];
    float acc[8];
    #pragma unroll
    for (int i = 0; i < 8; ++i) acc[i] = (float)h[i] * s;

    int p = rowstart[n] - e0, p1 = rowstart[n + 1] - e0;
    if (p1 <= CAPL2) {
        for (; p + 3 < p1; p += 4) {
            int s0 = eidx[p + 0], s1 = eidx[p + 1], s2 = eidx[p + 2], s3 = eidx[p + 3];
            float c0 = dinv[s0] * dn, c1 = dinv[s1] * dn;
            float c2 = dinv[s2] * dn, c3 = dinv[s3] * dn;
            bf16x8 v0 = *(const bf16x8*)&H2[s0 * OUT_DIM + j];
            bf16x8 v1 = *(const bf16x8*)&H2[s1 * OUT_DIM + j];
            bf16x8 v2 = *(const bf16x8*)&H2[s2 * OUT_DIM + j];
            bf16x8 v3 = *(const bf16x8*)&H2[s3 * OUT_DIM + j];
            #pragma unroll
            for (int i = 0; i < 8; ++i) acc[i] = fmaf((float)v0[i], c0, acc[i]);
            #pragma unroll
            for (int i = 0; i < 8; ++i) acc[i] = fmaf((float)v1[i], c1, acc[i]);
            #pragma unroll
            for (int i = 0; i < 8; ++i) acc[i] = fmaf((float)v2[i], c2, acc[i]);
            #pragma unroll
            for (int i = 0; i < 8; ++i) acc[i] = fmaf((float)v3[i], c3, acc[i]);
        }
        for (; p < p1; ++p) {
            int sidx = eidx[p];
            float c = dinv[sidx] * dn;
            bf16x8 v = *(const bf16x8*)&H2[sidx * OUT_DIM + j];
            #pragma unroll
            for (int i = 0; i < 8; ++i) acc[i] = fmaf((float)v[i], c, acc[i]);
        }
    } else {
        const int* ep = esrc + e0;
        for (; p + 3 < p1; p += 4) {
            int s0 = ep[p + 0], s1 = ep[p + 1], s2 = ep[p + 2], s3 = ep[p + 3];
            float c0 = dinv[s0] * dn, c1 = dinv[s1] * dn;
            float c2 = dinv[s2] * dn, c3 = dinv[s3] * dn;
            bf16x8 v0 = *(const bf16x8*)&H2[s0 * OUT_DIM + j];
            bf16x8 v1 = *(const bf16x8*)&H2[s1 * OUT_DIM + j];
            bf16x8 v2 = *(const bf16x8*)&H2[s2 * OUT_DIM + j];
            bf16x8 v3 = *(const bf16x8*)&H2[s3 * OUT_DIM + j];
            #pragma unroll
            for (int i = 0; i < 8; ++i) acc[i] = fmaf((float)v0[i], c0, acc[i]);
            #pragma unroll
            for (int i = 0; i < 8; ++i) acc[i] = fmaf((float)v1[i], c1, acc[i]);
            #pragma unroll
            for (int i = 0; i < 8; ++i) acc[i] = fmaf((float)v2[i], c2, acc[i]);
            #pragma unroll
            for (int i = 0; i < 8; ++i) acc[i] = fmaf((float)v3[i], c3, acc[i]);
        }
        for (; p < p1; ++p) {
            int sidx = ep[p];
            float c = dinv[sidx] * dn;
            bf16x8 v = *(const bf16x8*)&H2[sidx * OUT_DIM + j];
            #pragma unroll
            for (int i = 0; i < 8; ++i) acc[i] = fmaf((float)v[i], c, acc[i]);
        }
    }

    float4 bb0 = *(const float4*)&b2[j];
    float4 bb1 = *(const float4*)&b2[j + 4];
    float4 o0, o1;
    o0.x = fmaxf(acc[0] + bb0.x, 0.f);
    o0.y = fmaxf(acc[1] + bb0.y, 0.f);
    o0.z = fmaxf(acc[2] + bb0.z, 0.f);
    o0.w = fmaxf(acc[3] + bb0.w, 0.f);
    o1.x = fmaxf(acc[4] + bb1.x, 0.f);
    o1.y = fmaxf(acc[5] + bb1.y, 0.f);
    o1.z = fmaxf(acc[6] + bb1.z, 0.f);
    o1.w = fmaxf(acc[7] + bb1.w, 0.f);
    *(float4*)&OUT[n * OUT_DIM + j] = o0;
    *(float4*)&OUT[n * OUT_DIM + j + 4] = o1;
}

extern "C" void kernel_launch(void* const* d_in, const int* in_sizes, int n_in,
                              void* d_out, int out_size, void* d_ws, size_t ws_size,
                              hipStream_t stream) {
    const float* x  = (const float*)d_in[0];
    const int* ei   = (const int*)d_in[1];
    const float* W1 = (const float*)d_in[2];
    const float* b1 = (const float*)d_in[3];
    const float* W2 = (const float*)d_in[4];
    const float* b2 = (const float*)d_in[5];
    float* out = (float*)d_out;

    const int* src = ei;
    const int* dst = ei + N_EDGES;

    char* ws = (char*)d_ws;
    int*          cnt2     = (int*)         (ws + 0x000000);   // 400,384 B (becomes off2)
    int*          bsum     = (int*)         (ws + 0x080000);   // 1,564 B
    int*          rowstart = (int*)         (ws + 0x090000);   // 400,004 B
    float*        dinv     = (float*)       (ws + 0x100000);   // 400,000 B
    unsigned int* ebuf     = (unsigned int*)(ws + 0x180000);   // 6.4 MB
    int*          esrc     = (int*)         (ws + 0x800000);   // 6.4 MB
    __bf16*       h1       = (__bf16*)      (ws + 0xE80000);   // 25.6 MB
    __bf16*       h2       = (__bf16*)      (ws + 0x4280000);  // 12.8 MB

    // CSR build with gemm1 tile-blocks distributed as passengers
    k_hist_g   <<<NBLK3     + G_HIST,  512, 0, stream>>>(dst, cnt2, x, W1, h1);
    k_scan1_g  <<<NBLK_SCAN + G_SCAN1, 512, 0, stream>>>(cnt2, bsum, x, W1, h1);
    k_scan2_g  <<<1         + G_SCAN2, 512, 0, stream>>>(bsum, x, W1, h1);
    k_scatter_g<<<NBLK3     + G_SCAT,  512, 0, stream>>>(src, dst, cnt2, bsum, ebuf,
                                                         x, W1, h1);
    k_fine_g   <<<NBIN      + G_FINE,  512, 0, stream>>>(ebuf, cnt2, bsum, esrc,
                                                         rowstart, dinv, x, W1, h1);

    // fused layer-1 aggregation + layer-2 GEMM (AGG never hits HBM)
    k_gather1f<<<N_NODES / 16, 256, 0, stream>>>(rowstart, esrc, dinv, h1, b1, W2, h2);
    // layer 2 aggregation
    k_gather2<<<N_NODES / 32, 256, 0, stream>>>(rowstart, esrc, dinv, h2, b2, out);
}

// Round 12
// 306.370 us; speedup vs baseline: 1.1306x; 1.0468x over previous
//
#include <hip/hip_runtime.h>

#define N_NODES 100000
#define N_EDGES 1600000
#define IN_DIM 256
#define HIDDEN 128
#define OUT_DIM 64

#define NBIN 391       // coarse bins of 256 nodes: ceil(100000/256)
#define NBLK3 256      // histogram/scatter blocks
#define CHUNK 6250     // edges per block: N_EDGES / NBLK3 exactly
#define NMAT (NBIN * NBLK3)      // 100096 = scan length
#define NBLK_SCAN (NMAT / 256)   // 391 exactly
#define CAP 6144       // max edges per bin (mean 4096, sigma 64 -> 32 sigma margin)

// gemm1 passenger-tile distribution across the CSR chain (782 tiles total)
#define G_HIST  180
#define G_SCAN1 140
#define G_SCAT  180
#define G_FINE  282
#define OFF_HIST  0
#define OFF_SCAN1 180
#define OFF_SCAT  320
#define OFF_FINE  500

// LDS index-stage capacities (mean 256 / 512 edges; >=22 sigma margin)
#define CAPL1 640
#define CAPL2 1024

typedef __bf16 bf16x8 __attribute__((ext_vector_type(8)));
typedef __bf16 bf16x4 __attribute__((ext_vector_type(4)));
typedef float f32x4 __attribute__((ext_vector_type(4)));

// ---------------------------------------------------------------------------
// GEMM1 tile as a device function (512 threads): H[bid*128..+128][128] =
// bf16(X @ W1).  W1 staged in TWO 32KB halves into Bs (swizzled b128 writes,
// coalesced reads).  A direct global->reg.
// ---------------------------------------------------------------------------
__device__ __forceinline__ int bsw1h(int c, int kk) {   // kk in [0,128)
    return c * 128 + (kk ^ ((c & 7) << 3));
}

__device__ __forceinline__ void gemm1_tile(const float* __restrict__ X,
                                           const float* __restrict__ W1,
                                           __bf16* __restrict__ H,
                                           int bid, __bf16* Bs) {
    const int t = threadIdx.x;
    const int wave = t >> 6;
    const int lane = t & 63;
    const int lm = lane & 15;
    const int q = lane >> 4;
    const int row0 = bid * 128;
    const int g = row0 + wave * 16 + lm;   // the row this lane loads

    f32x4 acc[8] = {};

    for (int half = 0; half < 2; ++half) {
        __syncthreads();   // everyone done reading previous Bs image
        for (int p = 0; p < 4; ++p) {
            int i = t + 512 * p;        // 0..2047
            int c = i & 127;            // column
            int kg = i >> 7;            // k-group 0..15
            float v[8];
            #pragma unroll
            for (int j = 0; j < 8; ++j)
                v[j] = W1[(half * 128 + kg * 8 + j) * HIDDEN + c];
            bf16x8 w;
            #pragma unroll
            for (int j = 0; j < 8; ++j) w[j] = (__bf16)v[j];
            *(bf16x8*)&Bs[bsw1h(c, kg * 8)] = w;
        }
        __syncthreads();

        #pragma unroll
        for (int k0 = 0; k0 < 128; k0 += 32) {
            float4 v0 = make_float4(0.f, 0.f, 0.f, 0.f), v1 = v0;
            if (g < N_NODES) {
                const float* p = &X[(size_t)g * IN_DIM + half * 128 + k0 + q * 8];
                v0 = *(const float4*)p;
                v1 = *(const float4*)(p + 4);
            }
            bf16x8 a;
            a[0] = (__bf16)v0.x; a[1] = (__bf16)v0.y;
            a[2] = (__bf16)v0.z; a[3] = (__bf16)v0.w;
            a[4] = (__bf16)v1.x; a[5] = (__bf16)v1.y;
            a[6] = (__bf16)v1.z; a[7] = (__bf16)v1.w;
            #pragma unroll
            for (int ni = 0; ni < 8; ++ni) {
                bf16x8 bfr = *(const bf16x8*)&Bs[bsw1h(ni * 16 + lm, k0 + q * 8)];
                acc[ni] = __builtin_amdgcn_mfma_f32_16x16x32_bf16(a, bfr, acc[ni], 0, 0, 0);
            }
        }
    }

    #pragma unroll
    for (int r = 0; r < 4; ++r) {
        int grow = row0 + wave * 16 + q * 4 + r;
        if (grow < N_NODES) {
            #pragma unroll
            for (int ni = 0; ni < 8; ++ni)
                H[grow * HIDDEN + ni * 16 + lm] = (__bf16)acc[ni][r];
        }
    }
}

// ---------------------------------------------------------------------------
// P1 + gemm passengers: per-(bin,block) histogram (blocks < NBLK3), else a
// gemm1 tile.  Branch is block-uniform -> barriers safe.
// ---------------------------------------------------------------------------
__global__ __launch_bounds__(512, 4)
void k_hist_g(const int* __restrict__ dst, int* __restrict__ cnt2,
              const float* __restrict__ X, const float* __restrict__ W1,
              __bf16* __restrict__ H) {
    __shared__ __attribute__((aligned(16))) char smem[32768];
    if (blockIdx.x < NBLK3) {
        int* hist = (int*)smem;
        int t = threadIdx.x;
        for (int i = t; i < NBIN; i += 512) hist[i] = 0;
        __syncthreads();
        int base = blockIdx.x * CHUNK;
        for (int i = t; i < CHUNK; i += 512)
            atomicAdd(&hist[dst[base + i] >> 8], 1);
        __syncthreads();
        for (int k = t; k < NBIN; k += 512)
            cnt2[k * NBLK3 + blockIdx.x] = hist[k];
    } else {
        gemm1_tile(X, W1, H, OFF_HIST + (int)blockIdx.x - NBLK3, (__bf16*)smem);
    }
}

// ---------------------------------------------------------------------------
// P2 + passengers: per-bin-row exclusive scan (256 elems) + raw row sums.
// bsum[k] stays RAW (row total); consumers scan it themselves in LDS.
// ---------------------------------------------------------------------------
__global__ __launch_bounds__(512, 4)
void k_scan1_g(int* __restrict__ a, int* __restrict__ bsum,
               const float* __restrict__ X, const float* __restrict__ W1,
               __bf16* __restrict__ H) {
    __shared__ __attribute__((aligned(16))) char smem[32768];
    if (blockIdx.x < NBLK_SCAN) {
        int* tmp = (int*)smem;
        int t = threadIdx.x;
        int i = blockIdx.x * 256 + t;
        int v = 0;
        if (t < 256) { v = a[i]; tmp[t] = v; }
        __syncthreads();
        #pragma unroll
        for (int off = 1; off < 256; off <<= 1) {
            int p = (t >= off && t < 256) ? tmp[t - off] : 0;
            __syncthreads();
            if (t < 256) tmp[t] += p;
            __syncthreads();
        }
        if (t < 256) a[i] = tmp[t] - v;   // exclusive within bin-row
        if (t == 255) bsum[blockIdx.x] = tmp[255];
    } else {
        gemm1_tile(X, W1, H, OFF_SCAN1 + (int)blockIdx.x - NBLK_SCAN, (__bf16*)smem);
    }
}

// ---------------------------------------------------------------------------
// P3 + passengers: LDS counting-sort scatter.  Each block sorts its CHUNK
// edges by coarse bin in LDS, then streams each bin's run CONTIGUOUSLY to
// ebuf (run-sized coalesced writes instead of 6250 isolated 4-B scatters).
// Also scans raw bsum in LDS (replaces the deleted k_scan2 launch).
// ---------------------------------------------------------------------------
struct ScatSm {
    int bscan[392];
    int hist[392];
    int base[392];
    int curs[392];
    unsigned short binof[CHUNK];
    unsigned int sOut[CHUNK];
};   // ~43.8 KB

__global__ __launch_bounds__(512, 3)
void k_scatter_g(const int* __restrict__ src, const int* __restrict__ dst,
                 const int* __restrict__ off2, const int* __restrict__ bsum,
                 unsigned int* __restrict__ ebuf,
                 const float* __restrict__ X, const float* __restrict__ W1,
                 __bf16* __restrict__ H) {
    __shared__ __attribute__((aligned(16))) char smem[sizeof(ScatSm)];
    if (blockIdx.x < NBLK3) {
        ScatSm* sm = (ScatSm*)smem;
        const int t = threadIdx.x;
        const int b = blockIdx.x;
        int* tmp = (int*)sm->sOut;   // 512-int scratch (sOut unused until pass2)

        // --- scan raw bsum -> bscan (exclusive over 391) ---
        int v = (t < NBIN) ? bsum[t] : 0;
        tmp[t] = v;
        __syncthreads();
        #pragma unroll
        for (int off = 1; off < 512; off <<= 1) {
            int p = (t >= off) ? tmp[t - off] : 0;
            __syncthreads();
            tmp[t] += p;
            __syncthreads();
        }
        if (t < NBIN) sm->bscan[t] = tmp[t] - v;
        // --- local histogram of this block's edges ---
        if (t < NBIN) sm->hist[t] = 0;
        __syncthreads();
        const int ebase = b * CHUNK;
        for (int i = t; i < CHUNK; i += 512)
            atomicAdd(&sm->hist[dst[ebase + i] >> 8], 1);
        __syncthreads();
        // --- exclusive scan hist -> base ---
        int hv = (t < NBIN) ? sm->hist[t] : 0;
        tmp[t] = hv;
        __syncthreads();
        #pragma unroll
        for (int off = 1; off < 512; off <<= 1) {
            int p = (t >= off) ? tmp[t - off] : 0;
            __syncthreads();
            tmp[t] += p;
            __syncthreads();
        }
        if (t < NBIN) { sm->base[t] = tmp[t] - hv; sm->curs[t] = tmp[t] - hv; }
        if (t == 0) sm->base[NBIN] = CHUNK;
        __syncthreads();
        // --- slot -> bin map ---
        for (int k = t; k < NBIN; k += 512)
            for (int idx = sm->base[k]; idx < sm->base[k + 1]; ++idx)
                sm->binof[idx] = (unsigned short)k;
        __syncthreads();
        // --- place edges into sorted LDS order ---
        for (int i = t; i < CHUNK; i += 512) {
            int s = src[ebase + i], d = dst[ebase + i];
            int pos = atomicAdd(&sm->curs[d >> 8], 1);
            sm->sOut[pos] = ((unsigned)s << 8) | (unsigned)(d & 255);
        }
        __syncthreads();
        // --- stream runs out coalesced ---
        for (int i = t; i < CHUNK; i += 512) {
            int k = sm->binof[i];
            int gpos = off2[k * NBLK3 + b] + sm->bscan[k] + (i - sm->base[k]);
            ebuf[gpos] = sm->sOut[i];
        }
    } else {
        gemm1_tile(X, W1, H, OFF_SCAT + (int)blockIdx.x - NBLK3, (__bf16*)smem);
    }
}

// ---------------------------------------------------------------------------
// P4 + passengers: fine counting-sort within each bin; fuses dinv + rowstart.
// Computes its own e0 prefix from raw bsum (k_scan2 deleted).
// ---------------------------------------------------------------------------
struct FineSm {
    int hist[256];
    int tmp[256];
    int nodeoff[256];
    int cursor[256];
    unsigned int ed[CAP];
    int sOut[CAP];
};   // 53,248 B

__global__ __launch_bounds__(512, 4)
void k_fine_g(const unsigned int* __restrict__ ebuf, const int* __restrict__ bsum,
              int* __restrict__ esrc, int* __restrict__ rowstart,
              float* __restrict__ dinv,
              const float* __restrict__ X, const float* __restrict__ W1,
              __bf16* __restrict__ H) {
    __shared__ __attribute__((aligned(16))) char smem[sizeof(FineSm)];
    if (blockIdx.x < NBIN) {
        FineSm* sm = (FineSm*)smem;
        const int k = blockIdx.x;
        const int t = threadIdx.x;

        // e0 = sum_{k'<k} bsum[k'] via cooperative partial sums
        if (t == 0) sm->tmp[0] = 0;
        __syncthreads();
        int part = 0;
        for (int i = t; i < k; i += 512) part += bsum[i];
        if (part) atomicAdd(&sm->tmp[0], part);
        __syncthreads();
        const int e0 = sm->tmp[0];
        const int e1 = (k + 1 < NBIN) ? e0 + bsum[k] : N_EDGES;
        int m = e1 - e0;
        if (m > CAP) m = CAP;  // safety clamp (statistically unreachable)
        __syncthreads();

        if (t < 256) sm->hist[t] = 0;
        __syncthreads();
        for (int i = t; i < m; i += 512) {
            unsigned v = ebuf[e0 + i];
            sm->ed[i] = v;
            atomicAdd(&sm->hist[v & 255], 1);
        }
        __syncthreads();

        int v = (t < 256) ? sm->hist[t] : 0;
        if (t < 256) sm->tmp[t] = v;
        __syncthreads();
        #pragma unroll
        for (int off = 1; off < 256; off <<= 1) {
            int p = (t >= off && t < 256) ? sm->tmp[t - off] : 0;
            __syncthreads();
            if (t < 256) sm->tmp[t] += p;
            __syncthreads();
        }
        if (t < 256) {
            sm->nodeoff[t] = sm->tmp[t] - v;
            sm->cursor[t] = sm->tmp[t] - v;
        }
        __syncthreads();

        for (int i = t; i < m; i += 512) {
            unsigned e = sm->ed[i];
            int pos = atomicAdd(&sm->cursor[e & 255], 1);
            sm->sOut[pos] = (int)(e >> 8);
        }
        __syncthreads();

        for (int i = t; i < m; i += 512) esrc[e0 + i] = sm->sOut[i];

        if (t < 256) {
            int n = k * 256 + t;
            if (n < N_NODES) {
                rowstart[n] = e0 + sm->nodeoff[t];
                dinv[n] = rsqrtf((float)sm->hist[t] + 1.0f);
            }
        }
        if (k == 0 && t == 0) rowstart[N_NODES] = N_EDGES;
    } else {
        gemm1_tile(X, W1, H, OFF_FINE + (int)blockIdx.x - NBIN, (__bf16*)smem);
    }
}

// ---------------------------------------------------------------------------
// FUSED gather1 + gemm2 (proven 62us shape): grid 6250 x 256, 16 nodes/block,
// 16 lanes/node, LDS-staged esrc indices; 16 agg rows -> 4KB LDS tile
// (chunk-XOR swizzle); one barrier; 4 waves x 4 MFMAs -> H2 tile.
// ---------------------------------------------------------------------------
__device__ __forceinline__ int bsw2(int c, int kk) {
    return c * 128 + (kk ^ ((c & 7) << 3));
}

__launch_bounds__(256)
__global__ void k_gather1f(const int* __restrict__ rowstart, const int* __restrict__ esrc,
                           const float* __restrict__ dinv,
                           const __bf16* __restrict__ H, const float* __restrict__ b1,
                           const float* __restrict__ W2,
                           __bf16* __restrict__ H2) {
    __shared__ int eidx[CAPL1];                                    // 2.5 KB
    __shared__ __attribute__((aligned(16))) __bf16 As[16 * 128];   // 4 KB agg tile
    __shared__ __attribute__((aligned(16))) __bf16 Bs[64 * 128];   // 16 KB W2

    const int t = threadIdx.x;
    const int nb = blockIdx.x * 16;        // grid is exactly N_NODES/16
    const int e0 = rowstart[nb];
    const int m = rowstart[nb + 16] - e0;  // rowstart[N_NODES] is valid

    // stage W2 -> Bs bf16 [col][k] swizzled (b128 writes, coalesced reads)
    #pragma unroll
    for (int p = 0; p < 4; ++p) {
        int i = t + 256 * p;        // 0..1023
        int c = i & 63;             // column
        int kg = i >> 6;            // k-group 0..15
        float v[8];
        #pragma unroll
        for (int jj = 0; jj < 8; ++jj)
            v[jj] = W2[(kg * 8 + jj) * OUT_DIM + c];
        bf16x8 w;
        #pragma unroll
        for (int jj = 0; jj < 8; ++jj) w[jj] = (__bf16)v[jj];
        *(bf16x8*)&Bs[bsw2(c, kg * 8)] = w;
    }
    // stage this block's esrc range
    for (int i = t; i < m && i < CAPL1; i += 256) eidx[i] = esrc[e0 + i];
    __syncthreads();

    const int nl = t >> 4;         // local node 0..15
    const int n = nb + nl;
    const int jc = t & 15;         // 16B chunk index within row
    const int j = jc * 8;          // feature offset

    float dn = dinv[n];
    float s = dn * dn;
    bf16x8 h = *(const bf16x8*)&H[n * HIDDEN + j];
    float acc[8];
    #pragma unroll
    for (int i = 0; i < 8; ++i) acc[i] = (float)h[i] * s;

    int p = rowstart[n] - e0, p1 = rowstart[n + 1] - e0;
    if (p1 <= CAPL1) {
        // fast path: indices from LDS
        for (; p + 3 < p1; p += 4) {
            int s0 = eidx[p + 0], s1 = eidx[p + 1], s2 = eidx[p + 2], s3 = eidx[p + 3];
            float c0 = dinv[s0] * dn, c1 = dinv[s1] * dn;
            float c2 = dinv[s2] * dn, c3 = dinv[s3] * dn;
            bf16x8 v0 = *(const bf16x8*)&H[s0 * HIDDEN + j];
            bf16x8 v1 = *(const bf16x8*)&H[s1 * HIDDEN + j];
            bf16x8 v2 = *(const bf16x8*)&H[s2 * HIDDEN + j];
            bf16x8 v3 = *(const bf16x8*)&H[s3 * HIDDEN + j];
            #pragma unroll
            for (int i = 0; i < 8; ++i) acc[i] = fmaf((float)v0[i], c0, acc[i]);
            #pragma unroll
            for (int i = 0; i < 8; ++i) acc[i] = fmaf((float)v1[i], c1, acc[i]);
            #pragma unroll
            for (int i = 0; i < 8; ++i) acc[i] = fmaf((float)v2[i], c2, acc[i]);
            #pragma unroll
            for (int i = 0; i < 8; ++i) acc[i] = fmaf((float)v3[i], c3, acc[i]);
        }
        for (; p < p1; ++p) {
            int sidx = eidx[p];
            float c = dinv[sidx] * dn;
            bf16x8 v = *(const bf16x8*)&H[sidx * HIDDEN + j];
            #pragma unroll
            for (int i = 0; i < 8; ++i) acc[i] = fmaf((float)v[i], c, acc[i]);
        }
    } else {
        // fallback: global indices (statistically near-never)
        const int* ep = esrc + e0;
        for (; p + 3 < p1; p += 4) {
            int s0 = ep[p + 0], s1 = ep[p + 1], s2 = ep[p + 2], s3 = ep[p + 3];
            float c0 = dinv[s0] * dn, c1 = dinv[s1] * dn;
            float c2 = dinv[s2] * dn, c3 = dinv[s3] * dn;
            bf16x8 v0 = *(const bf16x8*)&H[s0 * HIDDEN + j];
            bf16x8 v1 = *(const bf16x8*)&H[s1 * HIDDEN + j];
            bf16x8 v2 = *(const bf16x8*)&H[s2 * HIDDEN + j];
            bf16x8 v3 = *(const bf16x8*)&H[s3 * HIDDEN + j];
            #pragma unroll
            for (int i = 0; i < 8; ++i) acc[i] = fmaf((float)v0[i], c0, acc[i]);
            #pragma unroll
            for (int i = 0; i < 8; ++i) acc[i] = fmaf((float)v1[i], c1, acc[i]);
            #pragma unroll
            for (int i = 0; i < 8; ++i) acc[i] = fmaf((float)v2[i], c2, acc[i]);
            #pragma unroll
            for (int i = 0; i < 8; ++i) acc[i] = fmaf((float)v3[i], c3, acc[i]);
        }
        for (; p < p1; ++p) {
            int sidx = ep[p];
            float c = dinv[sidx] * dn;
            bf16x8 v = *(const bf16x8*)&H[sidx * HIDDEN + j];
            #pragma unroll
            for (int i = 0; i < 8; ++i) acc[i] = fmaf((float)v[i], c, acc[i]);
        }
    }

    float4 bb0 = *(const float4*)&b1[j];
    float4 bb1 = *(const float4*)&b1[j + 4];
    bf16x8 o;
    o[0] = (__bf16)fmaxf(acc[0] + bb0.x, 0.f);
    o[1] = (__bf16)fmaxf(acc[1] + bb0.y, 0.f);
    o[2] = (__bf16)fmaxf(acc[2] + bb0.z, 0.f);
    o[3] = (__bf16)fmaxf(acc[3] + bb0.w, 0.f);
    o[4] = (__bf16)fmaxf(acc[4] + bb1.x, 0.f);
    o[5] = (__bf16)fmaxf(acc[5] + bb1.y, 0.f);
    o[6] = (__bf16)fmaxf(acc[6] + bb1.z, 0.f);
    o[7] = (__bf16)fmaxf(acc[7] + bb1.w, 0.f);
    // agg row -> LDS tile, chunk-XOR swizzle within the row (bijective)
    *(bf16x8*)&As[nl * 128 + (jc ^ (nl & 7)) * 8] = o;
    __syncthreads();

    // MFMA phase: wave w computes the 16-col quarter of the 16x64 H2 tile.
    const int wave = t >> 6;
    const int lane = t & 63;
    const int lm = lane & 15;
    const int q = lane >> 4;

    f32x4 acc2 = {};
    #pragma unroll
    for (int k0 = 0; k0 < HIDDEN; k0 += 32) {
        int c = (k0 >> 3) + q;     // chunk 0..15
        bf16x8 a = *(const bf16x8*)&As[lm * 128 + (c ^ (lm & 7)) * 8];
        bf16x8 bfr = *(const bf16x8*)&Bs[bsw2(wave * 16 + lm, k0 + q * 8)];
        acc2 = __builtin_amdgcn_mfma_f32_16x16x32_bf16(a, bfr, acc2, 0, 0, 0);
    }
    #pragma unroll
    for (int r = 0; r < 4; ++r)
        H2[(nb + q * 4 + r) * OUT_DIM + wave * 16 + lm] = (__bf16)acc2[r];
}

// ---------------------------------------------------------------------------
// gather layer2: OUT[n] = relu( sum coef*H2[src] + dinv^2*H2[n] + b2 )  (f32)
// 8 lanes x bf16x8 per node, 32 nodes/block, x4 unroll; LDS index staging.
// ---------------------------------------------------------------------------
__launch_bounds__(256)
__global__ void k_gather2(const int* __restrict__ rowstart, const int* __restrict__ esrc,
                          const float* __restrict__ dinv,
                          const __bf16* __restrict__ H2, const float* __restrict__ b2,
                          float* __restrict__ OUT) {
    __shared__ int eidx[CAPL2];
    const int nb = blockIdx.x * 32;        // grid is exactly N_NODES/32
    const int t = threadIdx.x;
    const int e0 = rowstart[nb];
    const int m = rowstart[nb + 32] - e0;
    for (int i = t; i < m && i < CAPL2; i += 256) eidx[i] = esrc[e0 + i];
    __syncthreads();

    const int n = nb + (t >> 3);
    const int j = (t & 7) * 8;

    float dn = dinv[n];
    float s = dn * dn;
    bf16x8 h = *(const bf16x8*)&H2[n * OUT_DIM + j];
    float acc[8];
    #pragma unroll
    for (int i = 0; i < 8; ++i) acc[i] = (float)h[i] * s;

    int p = rowstart[n] - e0, p1 = rowstart[n + 1] - e0;
    if (p1 <= CAPL2) {
        for (; p + 3 < p1; p += 4) {
            int s0 = eidx[p + 0], s1 = eidx[p + 1], s2 = eidx[p + 2], s3 = eidx[p + 3];
            float c0 = dinv[s0] * dn, c1 = dinv[s1] * dn;
            float c2 = dinv[s2] * dn, c3 = dinv[s3] * dn;
            bf16x8 v0 = *(const bf16x8*)&H2[s0 * OUT_DIM + j];
            bf16x8 v1 = *(const bf16x8*)&H2[s1 * OUT_DIM + j];
            bf16x8 v2 = *(const bf16x8*)&H2[s2 * OUT_DIM + j];
            bf16x8 v3 = *(const bf16x8*)&H2[s3 * OUT_DIM + j];
            #pragma unroll
            for (int i = 0; i < 8; ++i) acc[i] = fmaf((float)v0[i], c0, acc[i]);
            #pragma unroll
            for (int i = 0; i < 8; ++i) acc[i] = fmaf((float)v1[i], c1, acc[i]);
            #pragma unroll
            for (int i = 0; i < 8; ++i) acc[i] = fmaf((float)v2[i], c2, acc[i]);
            #pragma unroll
            for (int i = 0; i < 8; ++i) acc[i] = fmaf((float)v3[i], c3, acc[i]);
        }
        for (; p < p1; ++p) {
            int sidx = eidx[p];
            float c = dinv[sidx] * dn;
            bf16x8 v = *(const bf16x8*)&H2[sidx * OUT_DIM + j];
            #pragma unroll
            for (int i = 0; i < 8; ++i) acc[i] = fmaf((float)v[i], c, acc[i]);
        }
    } else {
        const int* ep = esrc + e0;
        for (; p + 3 < p1; p += 4) {
            int s0 = ep[p + 0], s1 = ep[p + 1], s2 = ep[p + 2], s3 = ep[p + 3];
            float c0 = dinv[s0] * dn, c1 = dinv[s1] * dn;
            float c2 = dinv[s2] * dn, c3 = dinv[s3] * dn;
            bf16x8 v0 = *(const bf16x8*)&H2[s0 * OUT_DIM + j];
            bf16x8 v1 = *(const bf16x8*)&H2[s1 * OUT_DIM + j];
            bf16x8 v2 = *(const bf16x8*)&H2[s2 * OUT_DIM + j];
            bf16x8 v3 = *(const bf16x8*)&H2[s3 * OUT_DIM + j];
            #pragma unroll
            for (int i = 0; i < 8; ++i) acc[i] = fmaf((float)v0[i], c0, acc[i]);
            #pragma unroll
            for (int i = 0; i < 8; ++i) acc[i] = fmaf((float)v1[i], c1, acc[i]);
            #pragma unroll
            for (int i = 0; i < 8; ++i) acc[i] = fmaf((float)v2[i], c2, acc[i]);
            #pragma unroll
            for (int i = 0; i < 8; ++i) acc[i] = fmaf((float)v3[i], c3, acc[i]);
        }
        for (; p < p1; ++p) {
            int sidx = ep[p];
            float c = dinv[sidx] * dn;
            bf16x8 v = *(const bf16x8*)&H2[sidx * OUT_DIM + j];
            #pragma unroll
            for (int i = 0; i < 8; ++i) acc[i] = fmaf((float)v[i], c, acc[i]);
        }
    }

    float4 bb0 = *(const float4*)&b2[j];
    float4 bb1 = *(const float4*)&b2[j + 4];
    float4 o0, o1;
    o0.x = fmaxf(acc[0] + bb0.x, 0.f);
    o0.y = fmaxf(acc[1] + bb0.y, 0.f);
    o0.z = fmaxf(acc[2] + bb0.z, 0.f);
    o0.w = fmaxf(acc[3] + bb0.w, 0.f);
    o1.x = fmaxf(acc[4] + bb1.x, 0.f);
    o1.y = fmaxf(acc[5] + bb1.y, 0.f);
    o1.z = fmaxf(acc[6] + bb1.z, 0.f);
    o1.w = fmaxf(acc[7] + bb1.w, 0.f);
    *(float4*)&OUT[n * OUT_DIM + j] = o0;
    *(float4*)&OUT[n * OUT_DIM + j + 4] = o1;
}

extern "C" void kernel_launch(void* const* d_in, const int* in_sizes, int n_in,
                              void* d_out, int out_size, void* d_ws, size_t ws_size,
                              hipStream_t stream) {
    const float* x  = (const float*)d_in[0];
    const int* ei   = (const int*)d_in[1];
    const float* W1 = (const float*)d_in[2];
    const float* b1 = (const float*)d_in[3];
    const float* W2 = (const float*)d_in[4];
    const float* b2 = (const float*)d_in[5];
    float* out = (float*)d_out;

    const int* src = ei;
    const int* dst = ei + N_EDGES;

    char* ws = (char*)d_ws;
    int*          cnt2     = (int*)         (ws + 0x000000);   // 400,384 B (becomes off2)
    int*          bsum     = (int*)         (ws + 0x080000);   // 1,564 B (raw row sums)
    int*          rowstart = (int*)         (ws + 0x090000);   // 400,004 B
    float*        dinv     = (float*)       (ws + 0x100000);   // 400,000 B
    unsigned int* ebuf     = (unsigned int*)(ws + 0x180000);   // 6.4 MB
    int*          esrc     = (int*)         (ws + 0x800000);   // 6.4 MB
    __bf16*       h1       = (__bf16*)      (ws + 0xE80000);   // 25.6 MB
    __bf16*       h2       = (__bf16*)      (ws + 0x4280000);  // 12.8 MB

    // CSR build with gemm1 tile-blocks distributed as passengers (4 launches)
    k_hist_g   <<<NBLK3     + G_HIST,  512, 0, stream>>>(dst, cnt2, x, W1, h1);
    k_scan1_g  <<<NBLK_SCAN + G_SCAN1, 512, 0, stream>>>(cnt2, bsum, x, W1, h1);
    k_scatter_g<<<NBLK3     + G_SCAT,  512, 0, stream>>>(src, dst, cnt2, bsum, ebuf,
                                                         x, W1, h1);
    k_fine_g   <<<NBIN      + G_FINE,  512, 0, stream>>>(ebuf, bsum, esrc,
                                                         rowstart, dinv, x, W1, h1);

    // fused layer-1 aggregation + layer-2 GEMM (AGG never hits HBM)
    k_gather1f<<<N_NODES / 16, 256, 0, stream>>>(rowstart, esrc, dinv, h1, b1, W2, h2);
    // layer 2 aggregation
    k_gather2<<<N_NODES / 32, 256, 0, stream>>>(rowstart, esrc, dinv, h2, b2, out);
}